// Round 2
// baseline (2004.330 us; speedup 1.0000x reference)
//
#include <hip/hip_runtime.h>

// SLabLinearAttention: B=4 N=4096 C=1024 H=16 HD=64 KH=5
// Round 2: fp32 correctness baseline, workspace cut to 197 MB (out2 aliases k)
// + ws_size diagnostic guard (absmax ~ 4096+MiB if ws too small).
//
// Stages:
//   K1 gemm_qkv : qkv = x @ qkv_w.T + b ; relu(q), relu(k+pos_enc); write q,k,v
//                 in head layout (bh=b*16+h, n, hd) fp32
//   K2 kv_part  : partial kv[c][d] = sum_j k[j][c]*v[j][d], partial ksum[c]
//   K3 kv_red   : reduce 4 partials
//   K4 attn_conv: out2 = (q@kv) * 1/(q.ksum+1e-6) + dwconv5(v); un-head-transpose.
//                 out2 WRITES INTO k's buffer (k dead after K2/K3; K4 reads q,v,kv,ksum only).
//                 5x5 conv on (n,1) image w/ pad 2 == 5-tap 1-D conv along n, kernel col 2.
//   K5 gemm_proj: out = out2 @ proj_w.T + proj_b

#define BB   4
#define NN   4096
#define CDIM 1024
#define NH   16
#define HDIM 64
#define BH   64        // BB*NH

__global__ __launch_bounds__(256) void k_fill_diag(float* __restrict__ out, int n, float val)
{
    int i = blockIdx.x * 256 + threadIdx.x;
    if (i < n) out[i] = val;
}

__global__ __launch_bounds__(256) void k_gemm_qkv(
    const float* __restrict__ x, const float* __restrict__ w,
    const float* __restrict__ bias, const float* __restrict__ pos_enc,
    float* __restrict__ q, float* __restrict__ k, float* __restrict__ v)
{
    __shared__ float As[16][68];   // [kk][row]
    __shared__ float Bs[16][68];   // [kk][col]
    const int t  = threadIdx.x;
    const int tx = t & 15, ty = t >> 4;
    const int col0 = blockIdx.x * 64;
    const int row0 = blockIdx.y * 64;
    const int lr = t >> 2;          // 0..63
    const int lk = (t & 3) * 4;     // 0,4,8,12
    float acc[4][4] = {};
    for (int k0 = 0; k0 < CDIM; k0 += 16) {
        float4 a = *reinterpret_cast<const float4*>(&x[(row0 + lr) * CDIM + k0 + lk]);
        float4 b = *reinterpret_cast<const float4*>(&w[(col0 + lr) * CDIM + k0 + lk]);
        __syncthreads();
        As[lk + 0][lr] = a.x; As[lk + 1][lr] = a.y; As[lk + 2][lr] = a.z; As[lk + 3][lr] = a.w;
        Bs[lk + 0][lr] = b.x; Bs[lk + 1][lr] = b.y; Bs[lk + 2][lr] = b.z; Bs[lk + 3][lr] = b.w;
        __syncthreads();
        #pragma unroll
        for (int kk = 0; kk < 16; ++kk) {
            float4 av = *reinterpret_cast<const float4*>(&As[kk][ty * 4]);
            float4 bv = *reinterpret_cast<const float4*>(&Bs[kk][tx * 4]);
            const float* ap = reinterpret_cast<const float*>(&av);
            const float* bp = reinterpret_cast<const float*>(&bv);
            #pragma unroll
            for (int ii = 0; ii < 4; ++ii)
                #pragma unroll
                for (int jj = 0; jj < 4; ++jj)
                    acc[ii][jj] += ap[ii] * bp[jj];
        }
    }
    const int part = col0 >> 10;     // 0=q 1=k 2=v, uniform per block
    float* dst = (part == 0) ? q : (part == 1) ? k : v;
    #pragma unroll
    for (int ii = 0; ii < 4; ++ii) {
        const int gr = row0 + ty * 4 + ii;
        const int b_ = gr >> 12, i_ = gr & 4095;
        #pragma unroll
        for (int jj = 0; jj < 4; ++jj) {
            const int gc = col0 + tx * 4 + jj;
            const int c  = gc & 1023;
            float val = acc[ii][jj] + bias[gc];
            if (part == 1) val += pos_enc[c];
            if (part != 2) val = fmaxf(val, 0.f);
            const int hh = c >> 6, d = c & 63;
            dst[((b_ * NH + hh) * NN + i_) * HDIM + d] = val;
        }
    }
}

__global__ __launch_bounds__(256) void k_kv_partial(
    const float* __restrict__ k, const float* __restrict__ v,
    float* __restrict__ part_kv, float* __restrict__ part_ks)
{
    __shared__ float ks[32 * 64];
    __shared__ float vs[32 * 64];
    const int bh = blockIdx.x;
    const int chunk = blockIdx.y;        // 4 chunks of 1024 tokens
    const int t = threadIdx.x;
    const int cg = t >> 4;
    const int dg = t & 15;
    const int lr = t >> 3;               // 0..31
    const int lc = (t & 7) * 8;
    const size_t base = (size_t)bh * NN * HDIM + (size_t)chunk * 1024 * HDIM;
    float acc[4][4] = {};
    float ksac[4] = {};
    for (int j0 = 0; j0 < 1024; j0 += 32) {
        float4 ka = *reinterpret_cast<const float4*>(&k[base + (j0 + lr) * 64 + lc]);
        float4 kb = *reinterpret_cast<const float4*>(&k[base + (j0 + lr) * 64 + lc + 4]);
        float4 va = *reinterpret_cast<const float4*>(&v[base + (j0 + lr) * 64 + lc]);
        float4 vb = *reinterpret_cast<const float4*>(&v[base + (j0 + lr) * 64 + lc + 4]);
        __syncthreads();
        *reinterpret_cast<float4*>(&ks[lr * 64 + lc])     = ka;
        *reinterpret_cast<float4*>(&ks[lr * 64 + lc + 4]) = kb;
        *reinterpret_cast<float4*>(&vs[lr * 64 + lc])     = va;
        *reinterpret_cast<float4*>(&vs[lr * 64 + lc + 4]) = vb;
        __syncthreads();
        #pragma unroll
        for (int j = 0; j < 32; ++j) {
            float4 k4 = *reinterpret_cast<const float4*>(&ks[j * 64 + cg * 4]);
            float4 v4 = *reinterpret_cast<const float4*>(&vs[j * 64 + dg * 4]);
            const float* kp = reinterpret_cast<const float*>(&k4);
            const float* vp = reinterpret_cast<const float*>(&v4);
            #pragma unroll
            for (int ii = 0; ii < 4; ++ii) {
                ksac[ii] += kp[ii];
                #pragma unroll
                for (int jj = 0; jj < 4; ++jj)
                    acc[ii][jj] += kp[ii] * vp[jj];
            }
        }
    }
    const int pb = (chunk * BH + bh);
    #pragma unroll
    for (int ii = 0; ii < 4; ++ii) {
        #pragma unroll
        for (int jj = 0; jj < 4; ++jj)
            part_kv[pb * 4096 + (cg * 4 + ii) * 64 + dg * 4 + jj] = acc[ii][jj];
        if (dg == 0) part_ks[pb * 64 + cg * 4 + ii] = ksac[ii];
    }
}

__global__ __launch_bounds__(256) void k_kv_reduce(
    const float* __restrict__ part_kv, const float* __restrict__ part_ks,
    float* __restrict__ kv, float* __restrict__ ksum)
{
    const int bh = blockIdx.x;
    const int t = threadIdx.x;
    #pragma unroll
    for (int r = 0; r < 16; ++r) {
        const int idx = r * 256 + t;
        float s = 0.f;
        #pragma unroll
        for (int ch = 0; ch < 4; ++ch) s += part_kv[(ch * BH + bh) * 4096 + idx];
        kv[bh * 4096 + idx] = s;
    }
    if (t < 64) {
        float s = 0.f;
        #pragma unroll
        for (int ch = 0; ch < 4; ++ch) s += part_ks[(ch * BH + bh) * 64 + t];
        ksum[bh * 64 + t] = s;
    }
}

__global__ __launch_bounds__(256) void k_attn_conv(
    const float* __restrict__ q, const float* __restrict__ v,
    const float* __restrict__ kv, const float* __restrict__ ksum,
    const float* __restrict__ dwc_w, const float* __restrict__ dwc_b,
    float* __restrict__ out2)
{
    __shared__ float kvs[4096];
    __shared__ float qs[4096];
    __shared__ float kss[64];
    const int bh = blockIdx.x;
    const int i0 = blockIdx.y * 64;
    const int t = threadIdx.x;
    const size_t hb = (size_t)bh * NN * HDIM;
    #pragma unroll
    for (int jj = 0; jj < 4; ++jj)
        *reinterpret_cast<float4*>(&kvs[t * 16 + jj * 4]) =
            *reinterpret_cast<const float4*>(&kv[bh * 4096 + t * 16 + jj * 4]);
    {
        const int r = t >> 2, c0 = (t & 3) * 16;
        #pragma unroll
        for (int jj = 0; jj < 4; ++jj)
            *reinterpret_cast<float4*>(&qs[r * 64 + c0 + jj * 4]) =
                *reinterpret_cast<const float4*>(&q[hb + (size_t)(i0 + r) * 64 + c0 + jj * 4]);
    }
    if (t < 64) kss[t] = ksum[bh * 64 + t];
    __syncthreads();
    const int wv = t >> 6, d = t & 63;
    float4 kvc[16], ks4[16];
    #pragma unroll
    for (int g = 0; g < 16; ++g) {
        float4 tmp;
        tmp.x = kvs[(g * 4 + 0) * 64 + d];
        tmp.y = kvs[(g * 4 + 1) * 64 + d];
        tmp.z = kvs[(g * 4 + 2) * 64 + d];
        tmp.w = kvs[(g * 4 + 3) * 64 + d];
        kvc[g] = tmp;
        ks4[g] = *reinterpret_cast<const float4*>(&kss[g * 4]);
    }
    float w5[5];
    #pragma unroll
    for (int dh = 0; dh < 5; ++dh) w5[dh] = dwc_w[d * 25 + dh * 5 + 2];  // col 2 only
    const float cbias = dwc_b[d];
    const int b_ = bh >> 4, h_ = bh & 15;
    float* obase = out2 + (size_t)b_ * NN * CDIM + h_ * 64 + d;
    for (int it = 0; it < 16; ++it) {
        const int il = wv * 16 + it;
        const int ig = i0 + il;
        float den = 1e-6f, num = 0.f;
        #pragma unroll
        for (int g = 0; g < 16; ++g) {
            float4 q4 = *reinterpret_cast<const float4*>(&qs[il * 64 + g * 4]);
            den += q4.x * ks4[g].x + q4.y * ks4[g].y + q4.z * ks4[g].z + q4.w * ks4[g].w;
            num += q4.x * kvc[g].x + q4.y * kvc[g].y + q4.z * kvc[g].z + q4.w * kvc[g].w;
        }
        const float z = 1.f / den;
        float fm = cbias;
        #pragma unroll
        for (int dh = 0; dh < 5; ++dh) {
            const int src = ig + dh - 2;
            if (src >= 0 && src < NN) fm += v[hb + (size_t)src * 64 + d] * w5[dh];
        }
        obase[(size_t)ig * CDIM] = num * z + fm;
    }
}

__global__ __launch_bounds__(256) void k_gemm_proj(
    const float* __restrict__ a, const float* __restrict__ w,
    const float* __restrict__ bias, float* __restrict__ out)
{
    __shared__ float As[16][68];
    __shared__ float Bs[16][68];
    const int t  = threadIdx.x;
    const int tx = t & 15, ty = t >> 4;
    const int col0 = blockIdx.x * 64;
    const int row0 = blockIdx.y * 64;
    const int lr = t >> 2;
    const int lk = (t & 3) * 4;
    float acc[4][4] = {};
    for (int k0 = 0; k0 < CDIM; k0 += 16) {
        float4 av = *reinterpret_cast<const float4*>(&a[(row0 + lr) * CDIM + k0 + lk]);
        float4 bv = *reinterpret_cast<const float4*>(&w[(col0 + lr) * CDIM + k0 + lk]);
        __syncthreads();
        As[lk + 0][lr] = av.x; As[lk + 1][lr] = av.y; As[lk + 2][lr] = av.z; As[lk + 3][lr] = av.w;
        Bs[lk + 0][lr] = bv.x; Bs[lk + 1][lr] = bv.y; Bs[lk + 2][lr] = bv.z; Bs[lk + 3][lr] = bv.w;
        __syncthreads();
        #pragma unroll
        for (int kk = 0; kk < 16; ++kk) {
            float4 a4 = *reinterpret_cast<const float4*>(&As[kk][ty * 4]);
            float4 b4 = *reinterpret_cast<const float4*>(&Bs[kk][tx * 4]);
            const float* ap = reinterpret_cast<const float*>(&a4);
            const float* bp = reinterpret_cast<const float*>(&b4);
            #pragma unroll
            for (int ii = 0; ii < 4; ++ii)
                #pragma unroll
                for (int jj = 0; jj < 4; ++jj)
                    acc[ii][jj] += ap[ii] * bp[jj];
        }
    }
    #pragma unroll
    for (int ii = 0; ii < 4; ++ii) {
        const int gr = row0 + ty * 4 + ii;
        #pragma unroll
        for (int jj = 0; jj < 4; ++jj) {
            const int gc = col0 + tx * 4 + jj;
            out[(size_t)gr * CDIM + gc] = acc[ii][jj] + bias[gc];
        }
    }
}

extern "C" void kernel_launch(void* const* d_in, const int* in_sizes, int n_in,
                              void* d_out, int out_size, void* d_ws, size_t ws_size,
                              hipStream_t stream)
{
    const float* x       = (const float*)d_in[0];
    const float* qkv_w   = (const float*)d_in[1];
    const float* qkv_b   = (const float*)d_in[2];
    const float* proj_w  = (const float*)d_in[3];
    const float* proj_b  = (const float*)d_in[4];
    const float* pos_enc = (const float*)d_in[5];
    const float* dwc_w   = (const float*)d_in[6];
    const float* dwc_b   = (const float*)d_in[7];

    // Workspace layout (floats): q | k(=out2 later) | v | part_kv | part_ks | kv | ksum
    const size_t QKV_ELEMS = 16777216;   // 64 MB each
    const size_t need_floats = 3 * QKV_ELEMS + 1048576 + 16384 + 262144 + 4096;
    const size_t need_bytes  = need_floats * 4;   // 206,651,392 B ~= 197.1 MiB

    if (ws_size < need_bytes) {
        // Diagnostic: encode available ws MiB into the output so the absmax
        // error reported by the harness tells us the real ws_size.
        const float diag = 4096.0f + (float)(ws_size >> 20);
        k_fill_diag<<<(out_size + 255) / 256, 256, 0, stream>>>((float*)d_out, out_size, diag);
        return;
    }

    float* ws      = (float*)d_ws;
    float* q       = ws;
    float* k       = q + QKV_ELEMS;      // reused as out2 after K3
    float* v       = k + QKV_ELEMS;
    float* part_kv = v + QKV_ELEMS;      // 4*64*64*64 = 1,048,576
    float* part_ks = part_kv + 1048576;  // 4*64*64    = 16,384
    float* kv      = part_ks + 16384;    // 64*64*64   = 262,144
    float* ksum    = kv + 262144;        // 64*64      = 4,096
    float* out2    = k;                  // alias: k dead after K2/K3
    float* out     = (float*)d_out;

    k_gemm_qkv <<<dim3(48, 256), 256, 0, stream>>>(x, qkv_w, qkv_b, pos_enc, q, k, v);
    k_kv_partial<<<dim3(64, 4),  256, 0, stream>>>(k, v, part_kv, part_ks);
    k_kv_reduce <<<64,           256, 0, stream>>>(part_kv, part_ks, kv, ksum);
    k_attn_conv <<<dim3(64, 64), 256, 0, stream>>>(q, v, kv, ksum, dwc_w, dwc_b, out2);
    k_gemm_proj <<<dim3(16, 256),256, 0, stream>>>(out2, proj_w, proj_b, out);
}

// Round 3
// 443.142 us; speedup vs baseline: 4.5230x; 4.5230x over previous
//
#include <hip/hip_runtime.h>

// SLabLinearAttention: B=4 N=4096 C=1024 H=16 HD=64 KH=5
// Round 3: bf16 MFMA GEMMs (m97 structure: 128x128 tile, BK=32, global_load_lds w16),
// fp32 attention core reading/writing bf16. ws ~148 MB (< 197 MB proven OK).
//
//   K0 f32->bf16 convert: x, qkv_w, proj_w
//   K1 gemm1_mfma: qkv = x @ qkv_w.T + b ; relu(q), relu(k+pos); q,k,v bf16 head layout
//   K2 kv_part   : partial kv[c][d] = sum_j k[j][c]*v[j][d], partial ksum[c]  (fp32)
//   K3 kv_red    : reduce 4 partials
//   K4 attn_conv : out2 = (q@kv)/(q.ksum+1e-6) + dwconv5(v); bf16 out2 (aliases k buf)
//                  (5x5 conv on (n,1) img pad2 == 5-tap 1-D conv along n, kernel col 2)
//   K5 gemm2_mfma: out = out2 @ proj_w.T + proj_b  (fp32 out)

#define BB   4
#define NN   4096
#define CDIM 1024
#define NH   16
#define HDIM 64
#define BH   64

typedef __attribute__((ext_vector_type(8))) short short8;
typedef __attribute__((ext_vector_type(4))) float f32x4;
typedef unsigned short u16;

__device__ __forceinline__ float b2f(short s) {
    union { unsigned u; float f; } c;
    c.u = ((unsigned)(unsigned short)s) << 16;
    return c.f;
}
__device__ __forceinline__ u16 f2b(float f) {   // RNE
    unsigned u = __float_as_uint(f);
    return (u16)((u + 0x7fffu + ((u >> 16) & 1u)) >> 16);
}
__device__ __forceinline__ void gload16(const void* g, void* l) {
    __builtin_amdgcn_global_load_lds((const __attribute__((address_space(1))) void*)g,
                                     (__attribute__((address_space(3))) void*)l, 16, 0, 0);
}

__global__ __launch_bounds__(256) void k_fill_diag(float* __restrict__ out, int n, float val)
{
    int i = blockIdx.x * 256 + threadIdx.x;
    if (i < n) out[i] = val;
}

__global__ __launch_bounds__(256) void k_f32_to_bf16(const float* __restrict__ in,
                                                     u16* __restrict__ out, int n4)
{
    int i = blockIdx.x * 256 + threadIdx.x;
    if (i < n4) {
        float4 v = reinterpret_cast<const float4*>(in)[i];
        ushort4 o;
        o.x = f2b(v.x); o.y = f2b(v.y); o.z = f2b(v.z); o.w = f2b(v.w);
        reinterpret_cast<ushort4*>(out)[i] = o;
    }
}

// ---------------- GEMM1: C[16384,3072] = x_bf16 @ qkvw_bf16^T, fused epilogue ------
__global__ __launch_bounds__(256) void k_gemm1_mfma(
    const u16* __restrict__ A,   // [16384][1024]
    const u16* __restrict__ Bw,  // [3072][1024]
    const float* __restrict__ bias, const float* __restrict__ pos_enc,
    u16* __restrict__ q, u16* __restrict__ kk_, u16* __restrict__ v)
{
    __shared__ u16 As[128 * 32];
    __shared__ u16 Bs[128 * 32];
    const int t = threadIdx.x;
    const int l = t & 63, w = t >> 6;
    const int wr = w >> 1, wc = w & 1;
    const int brow = blockIdx.y * 128;
    const int bcol = blockIdx.x * 128;
    const int sr = t >> 2;             // 0..63
    const int sk = (t & 3) * 8;        // 0,8,16,24
    const u16* gA = A  + (brow + sr) * 1024 + sk;
    const u16* gB = Bw + (bcol + sr) * 1024 + sk;
    char* ldsA = (char*)As + w * 1024;     // wave-uniform base; HW adds lane*16
    char* ldsB = (char*)Bs + w * 1024;

    f32x4 acc[4][4];
    #pragma unroll
    for (int m = 0; m < 4; ++m)
        #pragma unroll
        for (int n = 0; n < 4; ++n) acc[m][n] = (f32x4){0.f, 0.f, 0.f, 0.f};

    const int ar = wr * 64 + (l & 15);
    const int bc = wc * 64 + (l & 15);
    const int kfrag = (l >> 4) * 8;

    for (int k0 = 0; k0 < 1024; k0 += 32) {
        gload16(gA + k0,             ldsA);
        gload16(gA + k0 + 64 * 1024, ldsA + 4096);
        gload16(gB + k0,             ldsB);
        gload16(gB + k0 + 64 * 1024, ldsB + 4096);
        __syncthreads();
        short8 a[4], b[4];
        #pragma unroll
        for (int m = 0; m < 4; ++m)
            a[m] = *reinterpret_cast<const short8*>(&As[(ar + m * 16) * 32 + kfrag]);
        #pragma unroll
        for (int n = 0; n < 4; ++n)
            b[n] = *reinterpret_cast<const short8*>(&Bs[(bc + n * 16) * 32 + kfrag]);
        #pragma unroll
        for (int m = 0; m < 4; ++m)
            #pragma unroll
            for (int n = 0; n < 4; ++n)
                acc[m][n] = __builtin_amdgcn_mfma_f32_16x16x32_bf16(a[m], b[n], acc[m][n], 0, 0, 0);
        __syncthreads();
    }

    // epilogue: C/D layout col=l&15, row=(l>>4)*4+j  [m89]
    const int part = bcol >> 10;                 // uniform per block (128 | 1024)
    u16* dst = (part == 0) ? q : (part == 1) ? kk_ : v;
    const int col_base = bcol + wc * 64 + (l & 15);
    const int row_base = brow + wr * 64 + (l >> 4) * 4;
    #pragma unroll
    for (int n = 0; n < 4; ++n) {
        const int gc = col_base + n * 16;        // 0..3071
        const int c  = gc & 1023;
        float bv = bias[gc];
        if (part == 1) bv += pos_enc[c];
        const int h = c >> 6, d = c & 63;
        #pragma unroll
        for (int m = 0; m < 4; ++m)
            #pragma unroll
            for (int j = 0; j < 4; ++j) {
                const int gr = row_base + m * 16 + j;
                const int b_ = gr >> 12, i_ = gr & 4095;
                float val = acc[m][n][j] + bv;
                if (part != 2) val = fmaxf(val, 0.f);
                dst[(size_t)((b_ * NH + h) * NN + i_) * HDIM + d] = f2b(val);
            }
    }
}

// ---------------- K2: kv partials (bf16 in, fp32 out) ----------------
__global__ __launch_bounds__(256) void k_kv_partial(
    const u16* __restrict__ k, const u16* __restrict__ v,
    float* __restrict__ part_kv, float* __restrict__ part_ks)
{
    __shared__ float ks[32 * 64];
    __shared__ float vs[32 * 64];
    const int bh = blockIdx.x;
    const int chunk = blockIdx.y;
    const int t = threadIdx.x;
    const int cg = t >> 4;
    const int dg = t & 15;
    const int lr = t >> 3;               // 0..31
    const int lc = (t & 7) * 8;
    const size_t base = (size_t)bh * NN * HDIM + (size_t)chunk * 1024 * HDIM;
    float acc[4][4] = {};
    float ksac[4] = {};
    for (int j0 = 0; j0 < 1024; j0 += 32) {
        short8 kr = *reinterpret_cast<const short8*>(&k[base + (size_t)(j0 + lr) * 64 + lc]);
        short8 vr = *reinterpret_cast<const short8*>(&v[base + (size_t)(j0 + lr) * 64 + lc]);
        __syncthreads();
        #pragma unroll
        for (int j = 0; j < 8; ++j) {
            ks[lr * 64 + lc + j] = b2f(kr[j]);
            vs[lr * 64 + lc + j] = b2f(vr[j]);
        }
        __syncthreads();
        #pragma unroll
        for (int j = 0; j < 32; ++j) {
            float4 k4 = *reinterpret_cast<const float4*>(&ks[j * 64 + cg * 4]);
            float4 v4 = *reinterpret_cast<const float4*>(&vs[j * 64 + dg * 4]);
            const float* kp = reinterpret_cast<const float*>(&k4);
            const float* vp = reinterpret_cast<const float*>(&v4);
            #pragma unroll
            for (int ii = 0; ii < 4; ++ii) {
                ksac[ii] += kp[ii];
                #pragma unroll
                for (int jj = 0; jj < 4; ++jj)
                    acc[ii][jj] += kp[ii] * vp[jj];
            }
        }
    }
    const int pb = (chunk * BH + bh);
    #pragma unroll
    for (int ii = 0; ii < 4; ++ii) {
        #pragma unroll
        for (int jj = 0; jj < 4; ++jj)
            part_kv[pb * 4096 + (cg * 4 + ii) * 64 + dg * 4 + jj] = acc[ii][jj];
        if (dg == 0) part_ks[pb * 64 + cg * 4 + ii] = ksac[ii];
    }
}

__global__ __launch_bounds__(256) void k_kv_reduce(
    const float* __restrict__ part_kv, const float* __restrict__ part_ks,
    float* __restrict__ kv, float* __restrict__ ksum)
{
    const int bh = blockIdx.x;
    const int t = threadIdx.x;
    #pragma unroll
    for (int r = 0; r < 16; ++r) {
        const int idx = r * 256 + t;
        float s = 0.f;
        #pragma unroll
        for (int ch = 0; ch < 4; ++ch) s += part_kv[(ch * BH + bh) * 4096 + idx];
        kv[bh * 4096 + idx] = s;
    }
    if (t < 64) {
        float s = 0.f;
        #pragma unroll
        for (int ch = 0; ch < 4; ++ch) s += part_ks[(ch * BH + bh) * 64 + t];
        ksum[bh * 64 + t] = s;
    }
}

// ---------------- K4: attention finish + depthwise conv (bf16 in/out) ----------------
__global__ __launch_bounds__(256) void k_attn_conv(
    const u16* __restrict__ q, const u16* __restrict__ v,
    const float* __restrict__ kv, const float* __restrict__ ksum,
    const float* __restrict__ dwc_w, const float* __restrict__ dwc_b,
    u16* __restrict__ out2)
{
    __shared__ float kvs[4096];
    __shared__ float qs[4096];
    __shared__ float kss[64];
    const int bh = blockIdx.x;
    const int i0 = blockIdx.y * 64;
    const int t = threadIdx.x;
    const size_t hb = (size_t)bh * NN * HDIM;
    #pragma unroll
    for (int jj = 0; jj < 4; ++jj)
        *reinterpret_cast<float4*>(&kvs[t * 16 + jj * 4]) =
            *reinterpret_cast<const float4*>(&kv[bh * 4096 + t * 16 + jj * 4]);
    {
        const int r = t >> 2, c0 = (t & 3) * 16;
        short8 q0 = *reinterpret_cast<const short8*>(&q[hb + (size_t)(i0 + r) * 64 + c0]);
        short8 q1 = *reinterpret_cast<const short8*>(&q[hb + (size_t)(i0 + r) * 64 + c0 + 8]);
        #pragma unroll
        for (int j = 0; j < 8; ++j) {
            qs[r * 64 + c0 + j]     = b2f(q0[j]);
            qs[r * 64 + c0 + 8 + j] = b2f(q1[j]);
        }
    }
    if (t < 64) kss[t] = ksum[bh * 64 + t];
    __syncthreads();
    const int wv = t >> 6, d = t & 63;
    float4 kvc[16], ks4[16];
    #pragma unroll
    for (int g = 0; g < 16; ++g) {
        float4 tmp;
        tmp.x = kvs[(g * 4 + 0) * 64 + d];
        tmp.y = kvs[(g * 4 + 1) * 64 + d];
        tmp.z = kvs[(g * 4 + 2) * 64 + d];
        tmp.w = kvs[(g * 4 + 3) * 64 + d];
        kvc[g] = tmp;
        ks4[g] = *reinterpret_cast<const float4*>(&kss[g * 4]);
    }
    float w5[5];
    #pragma unroll
    for (int dh = 0; dh < 5; ++dh) w5[dh] = dwc_w[d * 25 + dh * 5 + 2];  // col 2 only
    const float cbias = dwc_b[d];
    const int b_ = bh >> 4, h_ = bh & 15;
    u16* obase = out2 + (size_t)b_ * NN * CDIM + h_ * 64 + d;
    for (int it = 0; it < 16; ++it) {
        const int il = wv * 16 + it;
        const int ig = i0 + il;
        float den = 1e-6f, num = 0.f;
        #pragma unroll
        for (int g = 0; g < 16; ++g) {
            float4 q4 = *reinterpret_cast<const float4*>(&qs[il * 64 + g * 4]);
            den += q4.x * ks4[g].x + q4.y * ks4[g].y + q4.z * ks4[g].z + q4.w * ks4[g].w;
            num += q4.x * kvc[g].x + q4.y * kvc[g].y + q4.z * kvc[g].z + q4.w * kvc[g].w;
        }
        const float z = 1.f / den;
        float fm = cbias;
        #pragma unroll
        for (int dh = 0; dh < 5; ++dh) {
            const int src = ig + dh - 2;
            if (src >= 0 && src < NN) fm += b2f(v[hb + (size_t)src * 64 + d]) * w5[dh];
        }
        obase[(size_t)ig * CDIM] = f2b(num * z + fm);
    }
}

// ---------------- GEMM2: out[16384,1024] = out2_bf16 @ projw_bf16^T + b ----------------
__global__ __launch_bounds__(256) void k_gemm2_mfma(
    const u16* __restrict__ A,   // [16384][1024]
    const u16* __restrict__ Bw,  // [1024][1024]
    const float* __restrict__ bias, float* __restrict__ out)
{
    __shared__ u16 As[128 * 32];
    __shared__ u16 Bs[128 * 32];
    const int t = threadIdx.x;
    const int l = t & 63, w = t >> 6;
    const int wr = w >> 1, wc = w & 1;
    const int brow = blockIdx.y * 128;
    const int bcol = blockIdx.x * 128;
    const int sr = t >> 2;
    const int sk = (t & 3) * 8;
    const u16* gA = A  + (brow + sr) * 1024 + sk;
    const u16* gB = Bw + (bcol + sr) * 1024 + sk;
    char* ldsA = (char*)As + w * 1024;
    char* ldsB = (char*)Bs + w * 1024;

    f32x4 acc[4][4];
    #pragma unroll
    for (int m = 0; m < 4; ++m)
        #pragma unroll
        for (int n = 0; n < 4; ++n) acc[m][n] = (f32x4){0.f, 0.f, 0.f, 0.f};

    const int ar = wr * 64 + (l & 15);
    const int bc = wc * 64 + (l & 15);
    const int kfrag = (l >> 4) * 8;

    for (int k0 = 0; k0 < 1024; k0 += 32) {
        gload16(gA + k0,             ldsA);
        gload16(gA + k0 + 64 * 1024, ldsA + 4096);
        gload16(gB + k0,             ldsB);
        gload16(gB + k0 + 64 * 1024, ldsB + 4096);
        __syncthreads();
        short8 a[4], b[4];
        #pragma unroll
        for (int m = 0; m < 4; ++m)
            a[m] = *reinterpret_cast<const short8*>(&As[(ar + m * 16) * 32 + kfrag]);
        #pragma unroll
        for (int n = 0; n < 4; ++n)
            b[n] = *reinterpret_cast<const short8*>(&Bs[(bc + n * 16) * 32 + kfrag]);
        #pragma unroll
        for (int m = 0; m < 4; ++m)
            #pragma unroll
            for (int n = 0; n < 4; ++n)
                acc[m][n] = __builtin_amdgcn_mfma_f32_16x16x32_bf16(a[m], b[n], acc[m][n], 0, 0, 0);
        __syncthreads();
    }

    const int col_base = bcol + wc * 64 + (l & 15);
    const int row_base = brow + wr * 64 + (l >> 4) * 4;
    #pragma unroll
    for (int n = 0; n < 4; ++n) {
        const int gc = col_base + n * 16;
        const float bv = bias[gc];
        #pragma unroll
        for (int m = 0; m < 4; ++m)
            #pragma unroll
            for (int j = 0; j < 4; ++j) {
                const int gr = row_base + m * 16 + j;
                out[(size_t)gr * CDIM + gc] = acc[m][n][j] + bv;
            }
    }
}

extern "C" void kernel_launch(void* const* d_in, const int* in_sizes, int n_in,
                              void* d_out, int out_size, void* d_ws, size_t ws_size,
                              hipStream_t stream)
{
    const float* x       = (const float*)d_in[0];
    const float* qkv_w   = (const float*)d_in[1];
    const float* qkv_b   = (const float*)d_in[2];
    const float* proj_w  = (const float*)d_in[3];
    const float* proj_b  = (const float*)d_in[4];
    const float* pos_enc = (const float*)d_in[5];
    const float* dwc_w   = (const float*)d_in[6];
    const float* dwc_b   = (const float*)d_in[7];

    // ws layout (bytes):
    //  q_b16 32M | k_b16 32M (=out2 later) | v_b16 32M | x_b16 32M | qkvw_b16 6M |
    //  projw_b16 2M | part_kv 4M | part_ks 64K | kv 1M | ksum 16K   => ~148 MB
    const size_t QKV = 16777216;                       // elements per q/k/v plane
    char* p = (char*)d_ws;
    u16* q_b    = (u16*)p;               p += QKV * 2;
    u16* k_b    = (u16*)p;               p += QKV * 2;  // reused as out2 bf16
    u16* v_b    = (u16*)p;               p += QKV * 2;
    u16* x_b    = (u16*)p;               p += QKV * 2;
    u16* qkvw_b = (u16*)p;               p += (size_t)3145728 * 2;
    u16* projw_b= (u16*)p;               p += (size_t)1048576 * 2;
    float* part_kv = (float*)p;          p += (size_t)1048576 * 4;
    float* part_ks = (float*)p;          p += (size_t)16384 * 4;
    float* kv      = (float*)p;          p += (size_t)262144 * 4;
    float* ksum    = (float*)p;          p += (size_t)4096 * 4;
    const size_t need_bytes = (size_t)(p - (char*)d_ws);

    if (ws_size < need_bytes) {
        const float diag = 4096.0f + (float)(ws_size >> 20);
        k_fill_diag<<<(out_size + 255) / 256, 256, 0, stream>>>((float*)d_out, out_size, diag);
        return;
    }

    u16* out2 = k_b;
    float* out = (float*)d_out;

    k_f32_to_bf16<<<16384, 256, 0, stream>>>(x,      x_b,     4194304);
    k_f32_to_bf16<<< 3072, 256, 0, stream>>>(qkv_w,  qkvw_b,   786432);
    k_f32_to_bf16<<< 1024, 256, 0, stream>>>(proj_w, projw_b,  262144);

    k_gemm1_mfma<<<dim3(24, 128), 256, 0, stream>>>(x_b, qkvw_b, qkv_b, pos_enc, q_b, k_b, v_b);
    k_kv_partial<<<dim3(64, 4),   256, 0, stream>>>(k_b, v_b, part_kv, part_ks);
    k_kv_reduce <<<64,            256, 0, stream>>>(part_kv, part_ks, kv, ksum);
    k_attn_conv <<<dim3(64, 64),  256, 0, stream>>>(q_b, v_b, kv, ksum, dwc_w, dwc_b, out2);
    k_gemm2_mfma<<<dim3(8, 128),  256, 0, stream>>>(out2, projw_b, proj_b, out);
}

// Round 4
// 321.162 us; speedup vs baseline: 6.2409x; 1.3798x over previous
//
#include <hip/hip_runtime.h>

// SLabLinearAttention: B=4 N=4096 C=1024 H=16 HD=64 KH=5
// Round 4: MFMA attention-finish.
//   K0 f32->bf16 convert: x, qkv_w, proj_w
//   K1 gemm1_mfma: qkv = x @ qkv_w.T + b ; relu(q), relu(k+pos); q,k,v bf16 head layout
//                  (+XCD-swizzle)
//   K2 kv_part   : partial kv[c][d] = sum_j k[j][c]*v[j][d], partial ksum[c]  (fp32)
//   K3 kv_red_t  : reduce 4 partials -> kvt bf16 [80][64] per head:
//                  rows 0..63 = kv^T (row d, col c), row 64 = ksum, rows 65..79 = 0
//   K4 attn_mfma : per 64-token wave strip: acc[m][n] = q @ kvt^T via MFMA (N=80 incl den),
//                  z=1/(den+1e-6); attn->LDS (stride 68); phase2: per-d rolling 5-tap conv
//                  on v + bias, coalesced bf16 store to out2 (aliases k buf).
//   K5 gemm2_mfma: out = out2 @ proj_w.T + proj_b (fp32 out, +XCD-swizzle)

#define BB   4
#define NN   4096
#define CDIM 1024
#define NH   16
#define HDIM 64
#define BH   64

typedef __attribute__((ext_vector_type(8))) short short8;
typedef __attribute__((ext_vector_type(4))) float f32x4;
typedef unsigned short u16;

__device__ __forceinline__ float b2f(short s) {
    union { unsigned u; float f; } c;
    c.u = ((unsigned)(unsigned short)s) << 16;
    return c.f;
}
__device__ __forceinline__ u16 f2b(float f) {   // RNE
    unsigned u = __float_as_uint(f);
    return (u16)((u + 0x7fffu + ((u >> 16) & 1u)) >> 16);
}
__device__ __forceinline__ void gload16(const void* g, void* l) {
    __builtin_amdgcn_global_load_lds((const __attribute__((address_space(1))) void*)g,
                                     (__attribute__((address_space(3))) void*)l, 16, 0, 0);
}

__global__ __launch_bounds__(256) void k_fill_diag(float* __restrict__ out, int n, float val)
{
    int i = blockIdx.x * 256 + threadIdx.x;
    if (i < n) out[i] = val;
}

__global__ __launch_bounds__(256) void k_f32_to_bf16(const float* __restrict__ in,
                                                     u16* __restrict__ out, int n4)
{
    int i = blockIdx.x * 256 + threadIdx.x;
    if (i < n4) {
        float4 v = reinterpret_cast<const float4*>(in)[i];
        ushort4 o;
        o.x = f2b(v.x); o.y = f2b(v.y); o.z = f2b(v.z); o.w = f2b(v.w);
        reinterpret_cast<ushort4*>(out)[i] = o;
    }
}

// ---------------- GEMM1: C[16384,3072] = x_bf16 @ qkvw_bf16^T, fused epilogue ------
__global__ __launch_bounds__(256) void k_gemm1_mfma(
    const u16* __restrict__ A,   // [16384][1024]
    const u16* __restrict__ Bw,  // [3072][1024]
    const float* __restrict__ bias, const float* __restrict__ pos_enc,
    u16* __restrict__ q, u16* __restrict__ kk_, u16* __restrict__ v)
{
    __shared__ u16 As[128 * 32];
    __shared__ u16 Bs[128 * 32];
    const int t = threadIdx.x;
    const int l = t & 63, w = t >> 6;
    const int wr = w >> 1, wc = w & 1;
    // bijective XCD swizzle (nwg = 24*128 = 3072, %8==0)
    const int nbx = gridDim.x, nwg = nbx * gridDim.y;
    const int lid = blockIdx.y * nbx + blockIdx.x;
    const int swz = (lid & 7) * (nwg >> 3) + (lid >> 3);
    const int bcol = (swz % nbx) * 128;
    const int brow = (swz / nbx) * 128;
    const int sr = t >> 2;             // 0..63
    const int sk = (t & 3) * 8;        // 0,8,16,24
    const u16* gA = A  + (brow + sr) * 1024 + sk;
    const u16* gB = Bw + (bcol + sr) * 1024 + sk;
    char* ldsA = (char*)As + w * 1024;     // wave-uniform base; HW adds lane*16
    char* ldsB = (char*)Bs + w * 1024;

    f32x4 acc[4][4];
    #pragma unroll
    for (int m = 0; m < 4; ++m)
        #pragma unroll
        for (int n = 0; n < 4; ++n) acc[m][n] = (f32x4){0.f, 0.f, 0.f, 0.f};

    const int ar = wr * 64 + (l & 15);
    const int bc = wc * 64 + (l & 15);
    const int kfrag = (l >> 4) * 8;

    for (int k0 = 0; k0 < 1024; k0 += 32) {
        gload16(gA + k0,             ldsA);
        gload16(gA + k0 + 64 * 1024, ldsA + 4096);
        gload16(gB + k0,             ldsB);
        gload16(gB + k0 + 64 * 1024, ldsB + 4096);
        __syncthreads();
        short8 a[4], b[4];
        #pragma unroll
        for (int m = 0; m < 4; ++m)
            a[m] = *reinterpret_cast<const short8*>(&As[(ar + m * 16) * 32 + kfrag]);
        #pragma unroll
        for (int n = 0; n < 4; ++n)
            b[n] = *reinterpret_cast<const short8*>(&Bs[(bc + n * 16) * 32 + kfrag]);
        #pragma unroll
        for (int m = 0; m < 4; ++m)
            #pragma unroll
            for (int n = 0; n < 4; ++n)
                acc[m][n] = __builtin_amdgcn_mfma_f32_16x16x32_bf16(a[m], b[n], acc[m][n], 0, 0, 0);
        __syncthreads();
    }

    // epilogue: C/D layout col=l&15, row=(l>>4)*4+j  [m89]
    const int part = bcol >> 10;                 // uniform per block
    u16* dst = (part == 0) ? q : (part == 1) ? kk_ : v;
    const int col_base = bcol + wc * 64 + (l & 15);
    const int row_base = brow + wr * 64 + (l >> 4) * 4;
    #pragma unroll
    for (int n = 0; n < 4; ++n) {
        const int gc = col_base + n * 16;        // 0..3071
        const int c  = gc & 1023;
        float bv = bias[gc];
        if (part == 1) bv += pos_enc[c];
        const int h = c >> 6, d = c & 63;
        #pragma unroll
        for (int m = 0; m < 4; ++m)
            #pragma unroll
            for (int j = 0; j < 4; ++j) {
                const int gr = row_base + m * 16 + j;
                const int b_ = gr >> 12, i_ = gr & 4095;
                float val = acc[m][n][j] + bv;
                if (part != 2) val = fmaxf(val, 0.f);
                dst[(size_t)((b_ * NH + h) * NN + i_) * HDIM + d] = f2b(val);
            }
    }
}

// ---------------- K2: kv partials (bf16 in, fp32 out) ----------------
__global__ __launch_bounds__(256) void k_kv_partial(
    const u16* __restrict__ k, const u16* __restrict__ v,
    float* __restrict__ part_kv, float* __restrict__ part_ks)
{
    __shared__ float ks[32 * 64];
    __shared__ float vs[32 * 64];
    const int bh = blockIdx.x;
    const int chunk = blockIdx.y;
    const int t = threadIdx.x;
    const int cg = t >> 4;
    const int dg = t & 15;
    const int lr = t >> 3;               // 0..31
    const int lc = (t & 7) * 8;
    const size_t base = (size_t)bh * NN * HDIM + (size_t)chunk * 1024 * HDIM;
    float acc[4][4] = {};
    float ksac[4] = {};
    for (int j0 = 0; j0 < 1024; j0 += 32) {
        short8 kr = *reinterpret_cast<const short8*>(&k[base + (size_t)(j0 + lr) * 64 + lc]);
        short8 vr = *reinterpret_cast<const short8*>(&v[base + (size_t)(j0 + lr) * 64 + lc]);
        __syncthreads();
        #pragma unroll
        for (int j = 0; j < 8; ++j) {
            ks[lr * 64 + lc + j] = b2f(kr[j]);
            vs[lr * 64 + lc + j] = b2f(vr[j]);
        }
        __syncthreads();
        #pragma unroll
        for (int j = 0; j < 32; ++j) {
            float4 k4 = *reinterpret_cast<const float4*>(&ks[j * 64 + cg * 4]);
            float4 v4 = *reinterpret_cast<const float4*>(&vs[j * 64 + dg * 4]);
            const float* kp = reinterpret_cast<const float*>(&k4);
            const float* vp = reinterpret_cast<const float*>(&v4);
            #pragma unroll
            for (int ii = 0; ii < 4; ++ii) {
                ksac[ii] += kp[ii];
                #pragma unroll
                for (int jj = 0; jj < 4; ++jj)
                    acc[ii][jj] += kp[ii] * vp[jj];
            }
        }
    }
    const int pb = (chunk * BH + bh);
    #pragma unroll
    for (int ii = 0; ii < 4; ++ii) {
        #pragma unroll
        for (int jj = 0; jj < 4; ++jj)
            part_kv[pb * 4096 + (cg * 4 + ii) * 64 + dg * 4 + jj] = acc[ii][jj];
        if (dg == 0) part_ks[pb * 64 + cg * 4 + ii] = ksac[ii];
    }
}

// ---------------- K3: reduce partials -> kvt bf16 [80][64] per head ----------------
__global__ __launch_bounds__(256) void k_kv_reduce_t(
    const float* __restrict__ part_kv, const float* __restrict__ part_ks,
    u16* __restrict__ kvt)
{
    const int bh = blockIdx.x;
    const int t = threadIdx.x;
    u16* base = kvt + bh * 5120;          // 80*64
    #pragma unroll
    for (int r = 0; r < 16; ++r) {
        const int idx = r * 256 + t;       // idx = c*64 + d
        const int c = idx >> 6, d = idx & 63;
        float s = 0.f;
        #pragma unroll
        for (int ch = 0; ch < 4; ++ch) s += part_kv[(ch * BH + bh) * 4096 + idx];
        base[d * 64 + c] = f2b(s);         // transposed: row d, col c
    }
    if (t < 64) {
        float s = 0.f;
        #pragma unroll
        for (int ch = 0; ch < 4; ++ch) s += part_ks[(ch * BH + bh) * 64 + t];
        base[4096 + t] = f2b(s);           // row 64 = ksum
    }
    for (int z = t; z < 960; z += 256) base[4160 + z] = 0;   // rows 65..79 = 0
}

// ---------------- K4: MFMA attention finish + depthwise conv ----------------
__global__ __launch_bounds__(256) void k_attn_mfma(
    const u16* __restrict__ q, const u16* __restrict__ v,
    const u16* __restrict__ kvt,
    const float* __restrict__ dwc_w, const float* __restrict__ dwc_b,
    u16* __restrict__ out2)
{
    __shared__ u16 att[4][64 * 68];        // per-wave 64-token strip, stride 68 (bank-safe)
    const int t = threadIdx.x;
    const int l = t & 63, w = t >> 6;
    const int bh = blockIdx.x;
    const int tb = blockIdx.y * 256 + w * 64;     // token base of this wave
    const size_t hb = (size_t)bh * NN * HDIM;
    const u16* qb  = q + hb + (size_t)tb * HDIM;
    const u16* kvb = kvt + bh * 5120;

    const int fr = l & 15;                  // frag row/col index
    const int kfrag = (l >> 4) * 8;

    short8 bfr[5][2];
    #pragma unroll
    for (int n = 0; n < 5; ++n)
        #pragma unroll
        for (int ks = 0; ks < 2; ++ks)
            bfr[n][ks] = *reinterpret_cast<const short8*>(&kvb[(n * 16 + fr) * 64 + ks * 32 + kfrag]);

    f32x4 acc[4][5];
    #pragma unroll
    for (int m = 0; m < 4; ++m)
        #pragma unroll
        for (int n = 0; n < 5; ++n) acc[m][n] = (f32x4){0.f, 0.f, 0.f, 0.f};

    #pragma unroll
    for (int m = 0; m < 4; ++m)
        #pragma unroll
        for (int ks = 0; ks < 2; ++ks) {
            short8 a = *reinterpret_cast<const short8*>(&qb[(m * 16 + fr) * 64 + ks * 32 + kfrag]);
            #pragma unroll
            for (int n = 0; n < 5; ++n)
                acc[m][n] = __builtin_amdgcn_mfma_f32_16x16x32_bf16(a, bfr[n][ks], acc[m][n], 0, 0, 0);
        }

    // epilogue: col = l&15, row = (l>>4)*4 + j; den = col 64 (n=4, lanes fr==0)
    #pragma unroll
    for (int m = 0; m < 4; ++m)
        #pragma unroll
        for (int j = 0; j < 4; ++j) {
            const float den = __shfl(acc[m][4][j], l & 48);
            const float z = 1.f / (den + 1e-6f);
            const int row = m * 16 + (l >> 4) * 4 + j;
            #pragma unroll
            for (int n = 0; n < 4; ++n)
                att[w][row * 68 + fr + n * 16] = f2b(acc[m][n][j] * z);
        }
    __syncthreads();

    // phase 2: lane = d column; rolling 5-tap conv along tokens; coalesced store
    const int d = l;
    float w5[5];
    #pragma unroll
    for (int dh = 0; dh < 5; ++dh) w5[dh] = dwc_w[d * 25 + dh * 5 + 2];  // kernel col 2 only
    const float cbias = dwc_b[d];
    const int b_ = bh >> 4, h_ = bh & 15;
    u16* obase = out2 + (size_t)b_ * NN * CDIM + (size_t)h_ * 64 + d;
    float win[5];
    #pragma unroll
    for (int p = 0; p < 4; ++p) {
        const int src = tb - 2 + p;
        win[p] = (src >= 0 && src < NN) ? b2f(v[hb + (size_t)src * 64 + d]) : 0.f;
    }
    for (int it = 0; it < 64; ++it) {
        const int srcn = tb + it + 2;
        win[4] = (srcn < NN) ? b2f(v[hb + (size_t)srcn * 64 + d]) : 0.f;
        const float fm = cbias + w5[0] * win[0] + w5[1] * win[1] + w5[2] * win[2]
                               + w5[3] * win[3] + w5[4] * win[4];
        const float attn = b2f((short)att[w][it * 68 + d]);
        obase[(size_t)(tb + it) * CDIM] = f2b(attn + fm);
        win[0] = win[1]; win[1] = win[2]; win[2] = win[3]; win[3] = win[4];
    }
}

// ---------------- GEMM2: out[16384,1024] = out2_bf16 @ projw_bf16^T + b ----------------
__global__ __launch_bounds__(256) void k_gemm2_mfma(
    const u16* __restrict__ A,   // [16384][1024]
    const u16* __restrict__ Bw,  // [1024][1024]
    const float* __restrict__ bias, float* __restrict__ out)
{
    __shared__ u16 As[128 * 32];
    __shared__ u16 Bs[128 * 32];
    const int t = threadIdx.x;
    const int l = t & 63, w = t >> 6;
    const int wr = w >> 1, wc = w & 1;
    // bijective XCD swizzle (nwg = 8*128 = 1024, %8==0)
    const int nbx = gridDim.x, nwg = nbx * gridDim.y;
    const int lid = blockIdx.y * nbx + blockIdx.x;
    const int swz = (lid & 7) * (nwg >> 3) + (lid >> 3);
    const int bcol = (swz % nbx) * 128;
    const int brow = (swz / nbx) * 128;
    const int sr = t >> 2;
    const int sk = (t & 3) * 8;
    const u16* gA = A  + (brow + sr) * 1024 + sk;
    const u16* gB = Bw + (bcol + sr) * 1024 + sk;
    char* ldsA = (char*)As + w * 1024;
    char* ldsB = (char*)Bs + w * 1024;

    f32x4 acc[4][4];
    #pragma unroll
    for (int m = 0; m < 4; ++m)
        #pragma unroll
        for (int n = 0; n < 4; ++n) acc[m][n] = (f32x4){0.f, 0.f, 0.f, 0.f};

    const int ar = wr * 64 + (l & 15);
    const int bc = wc * 64 + (l & 15);
    const int kfrag = (l >> 4) * 8;

    for (int k0 = 0; k0 < 1024; k0 += 32) {
        gload16(gA + k0,             ldsA);
        gload16(gA + k0 + 64 * 1024, ldsA + 4096);
        gload16(gB + k0,             ldsB);
        gload16(gB + k0 + 64 * 1024, ldsB + 4096);
        __syncthreads();
        short8 a[4], b[4];
        #pragma unroll
        for (int m = 0; m < 4; ++m)
            a[m] = *reinterpret_cast<const short8*>(&As[(ar + m * 16) * 32 + kfrag]);
        #pragma unroll
        for (int n = 0; n < 4; ++n)
            b[n] = *reinterpret_cast<const short8*>(&Bs[(bc + n * 16) * 32 + kfrag]);
        #pragma unroll
        for (int m = 0; m < 4; ++m)
            #pragma unroll
            for (int n = 0; n < 4; ++n)
                acc[m][n] = __builtin_amdgcn_mfma_f32_16x16x32_bf16(a[m], b[n], acc[m][n], 0, 0, 0);
        __syncthreads();
    }

    const int col_base = bcol + wc * 64 + (l & 15);
    const int row_base = brow + wr * 64 + (l >> 4) * 4;
    #pragma unroll
    for (int n = 0; n < 4; ++n) {
        const int gc = col_base + n * 16;
        const float bv = bias[gc];
        #pragma unroll
        for (int m = 0; m < 4; ++m)
            #pragma unroll
            for (int j = 0; j < 4; ++j) {
                const int gr = row_base + m * 16 + j;
                out[(size_t)gr * CDIM + gc] = acc[m][n][j] + bv;
            }
    }
}

extern "C" void kernel_launch(void* const* d_in, const int* in_sizes, int n_in,
                              void* d_out, int out_size, void* d_ws, size_t ws_size,
                              hipStream_t stream)
{
    const float* x       = (const float*)d_in[0];
    const float* qkv_w   = (const float*)d_in[1];
    const float* qkv_b   = (const float*)d_in[2];
    const float* proj_w  = (const float*)d_in[3];
    const float* proj_b  = (const float*)d_in[4];
    const float* pos_enc = (const float*)d_in[5];
    const float* dwc_w   = (const float*)d_in[6];
    const float* dwc_b   = (const float*)d_in[7];

    const size_t QKV = 16777216;                       // elements per q/k/v plane
    char* p = (char*)d_ws;
    u16* q_b    = (u16*)p;               p += QKV * 2;
    u16* k_b    = (u16*)p;               p += QKV * 2;  // reused as out2 bf16
    u16* v_b    = (u16*)p;               p += QKV * 2;
    u16* x_b    = (u16*)p;               p += QKV * 2;
    u16* qkvw_b = (u16*)p;               p += (size_t)3145728 * 2;
    u16* projw_b= (u16*)p;               p += (size_t)1048576 * 2;
    float* part_kv = (float*)p;          p += (size_t)1048576 * 4;
    float* part_ks = (float*)p;          p += (size_t)16384 * 4;
    u16* kvt       = (u16*)p;            p += (size_t)(64 * 5120) * 2;
    const size_t need_bytes = (size_t)(p - (char*)d_ws);

    if (ws_size < need_bytes) {
        const float diag = 4096.0f + (float)(ws_size >> 20);
        k_fill_diag<<<(out_size + 255) / 256, 256, 0, stream>>>((float*)d_out, out_size, diag);
        return;
    }

    u16* out2 = k_b;
    float* out = (float*)d_out;

    k_f32_to_bf16<<<16384, 256, 0, stream>>>(x,      x_b,     4194304);
    k_f32_to_bf16<<< 3072, 256, 0, stream>>>(qkv_w,  qkvw_b,   786432);
    k_f32_to_bf16<<< 1024, 256, 0, stream>>>(proj_w, projw_b,  262144);

    k_gemm1_mfma <<<dim3(24, 128), 256, 0, stream>>>(x_b, qkvw_b, qkv_b, pos_enc, q_b, k_b, v_b);
    k_kv_partial <<<dim3(64, 4),   256, 0, stream>>>(k_b, v_b, part_kv, part_ks);
    k_kv_reduce_t<<<64,            256, 0, stream>>>(part_kv, part_ks, kvt);
    k_attn_mfma  <<<dim3(64, 16),  256, 0, stream>>>(q_b, v_b, kvt, dwc_w, dwc_b, out2);
    k_gemm2_mfma <<<dim3(8, 128),  256, 0, stream>>>(out2, projw_b, proj_b, out);
}

// Round 5
// 315.410 us; speedup vs baseline: 6.3547x; 1.0182x over previous
//
#include <hip/hip_runtime.h>

// SLabLinearAttention: B=4 N=4096 C=1024 H=16 HD=64 KH=5
// Round 5: 256x256-tile, BK=32, 8-wave GEMMs with counted-vmcnt pipeline,
// LDS XOR swizzle (2-way, free) and setprio. Attention stages unchanged from R4.
//
//   K0 f32->bf16 convert: x, qkv_w, proj_w
//   K1 gemm1_256 : qkv = x @ qkv_w.T + b ; relu(q), relu(k+pos); q,k,v bf16 head layout
//   K2 kv_part   : partial kv[c][d] = sum_j k[j][c]*v[j][d], partial ksum[c]  (fp32)
//   K3 kv_red_t  : reduce -> kvt bf16 [80][64]/head (kv^T | ksum | zeros)
//   K4 attn_mfma : q@kvt^T via MFMA (den = col 64), z=1/(den+1e-6); +5-tap conv on v
//   K5 gemm2_256 : out = out2 @ proj_w.T + proj_b (fp32 out)

#define BB   4
#define NN   4096
#define CDIM 1024
#define NH   16
#define HDIM 64
#define BH   64

typedef __attribute__((ext_vector_type(8))) short short8;
typedef __attribute__((ext_vector_type(4))) float f32x4;
typedef unsigned short u16;

__device__ __forceinline__ float b2f(short s) {
    union { unsigned u; float f; } c;
    c.u = ((unsigned)(unsigned short)s) << 16;
    return c.f;
}
__device__ __forceinline__ u16 f2b(float f) {   // RNE
    unsigned u = __float_as_uint(f);
    return (u16)((u + 0x7fffu + ((u >> 16) & 1u)) >> 16);
}
__device__ __forceinline__ void gload16(const void* g, void* l) {
    __builtin_amdgcn_global_load_lds((const __attribute__((address_space(1))) void*)g,
                                     (__attribute__((address_space(3))) void*)l, 16, 0, 0);
}

__global__ __launch_bounds__(256) void k_fill_diag(float* __restrict__ out, int n, float val)
{
    int i = blockIdx.x * 256 + threadIdx.x;
    if (i < n) out[i] = val;
}

__global__ __launch_bounds__(256) void k_f32_to_bf16(const float* __restrict__ in,
                                                     u16* __restrict__ out, int n4)
{
    int i = blockIdx.x * 256 + threadIdx.x;
    if (i < n4) {
        float4 v = reinterpret_cast<const float4*>(in)[i];
        ushort4 o;
        o.x = f2b(v.x); o.y = f2b(v.y); o.z = f2b(v.z); o.w = f2b(v.w);
        reinterpret_cast<ushort4*>(out)[i] = o;
    }
}

// ============ 256x256 BK=32 pipelined GEMM core (shared by gemm1/gemm2) ============
// LDS 64KB: buf0{A@0,B@16KB}, buf1{A@32KB,B@48KB}. A/B tiles [256 rows][32 k] u16,
// rows = 64B = 4 x 16B chunks, physical chunk p holds logical chunk p ^ ((row>>1)&3).
// Stage: thread t loads rows {t>>2, 128+t>>2}, global k-chunk (l&3)^((l>>3)&3) ->
//        LDS linear (wave base w*1024 + lane*16) == row*64 + (l&3)*16.  [rule #21]
// Read: frag row = base+m*16+(l&15); phys chunk = (l>>4) ^ ((l>>1)&3)  -> 2-way, free.
// Pipeline: 2-deep: stage(kt+2) issued mid-iter; s_waitcnt vmcnt(4) (never 0) before
// the buffer-swap barrier. Raw s_barrier + lgkmcnt(0) + sched_barrier(0) fences.

#define GEMM_PROLOGUE_AND_LOOP(EXTRA_BCOLS)                                              \
    const int t = threadIdx.x;                                                           \
    const int l = t & 63, w = t >> 6;                                                    \
    const int wr = w >> 2, wc = w & 3;                                                   \
    const int qa = ((l & 3) ^ ((l >> 3) & 3)) * 8;                                       \
    const int srow = t >> 2;                                                             \
    const u16* gA = A  + (size_t)(brow + srow) * 1024 + qa;                              \
    const u16* gB = Bw + (size_t)(bcol + srow) * 1024 + qa;                              \
    const int fr = l & 15;                                                               \
    const int phys8 = ((l >> 4) ^ ((l >> 1) & 3)) * 8;                                   \
    const int arow0 = wr * 128 + fr;                                                     \
    const int bfr0  = wc * 64 + fr;                                                      \
    f32x4 acc[8][4];                                                                     \
    _Pragma("unroll")                                                                    \
    for (int m = 0; m < 8; ++m)                                                          \
        _Pragma("unroll")                                                                \
        for (int n = 0; n < 4; ++n) acc[m][n] = (f32x4){0.f, 0.f, 0.f, 0.f};             \
    /* STAGE(buf, kt): 4 gload16 (2 A + 2 B) */                                          \
    auto STAGE = [&](int buf, int kt) {                                                  \
        const int kof = kt * 32;                                                         \
        char* lb = (char*)lds + buf * 32768 + w * 1024;                                  \
        gload16(gA + kof,          lb);                                                  \
        gload16(gA + 131072 + kof, lb + 8192);                                           \
        gload16(gB + kof,          lb + 16384);                                          \
        gload16(gB + 131072 + kof, lb + 24576);                                          \
    };                                                                                   \
    STAGE(0, 0);                                                                         \
    STAGE(1, 1);                                                                         \
    asm volatile("s_waitcnt vmcnt(4)" ::: "memory");                                     \
    __builtin_amdgcn_sched_barrier(0);                                                   \
    __builtin_amdgcn_s_barrier();                                                        \
    __builtin_amdgcn_sched_barrier(0);                                                   \
    for (int kt = 0; kt < 32; ++kt) {                                                    \
        const int cur = kt & 1;                                                          \
        const int ab = cur * 16384;                                                      \
        short8 af[8], bf[4];                                                             \
        _Pragma("unroll")                                                                \
        for (int n = 0; n < 4; ++n)                                                      \
            bf[n] = *reinterpret_cast<const short8*>(                                    \
                        &lds[ab + 8192 + (bfr0 + n * 16) * 32 + phys8]);                 \
        _Pragma("unroll")                                                                \
        for (int m = 0; m < 8; ++m)                                                      \
            af[m] = *reinterpret_cast<const short8*>(                                    \
                        &lds[ab + (arow0 + m * 16) * 32 + phys8]);                       \
        asm volatile("s_waitcnt lgkmcnt(0)" ::: "memory");                               \
        __builtin_amdgcn_sched_barrier(0);                                               \
        __builtin_amdgcn_s_barrier();   /* all waves done reading buf[cur] */            \
        __builtin_amdgcn_sched_barrier(0);                                               \
        if (kt + 2 < 32) STAGE(cur, kt + 2);                                             \
        __builtin_amdgcn_s_setprio(1);                                                   \
        _Pragma("unroll")                                                                \
        for (int m = 0; m < 8; ++m)                                                      \
            _Pragma("unroll")                                                            \
            for (int n = 0; n < 4; ++n)                                                  \
                acc[m][n] = __builtin_amdgcn_mfma_f32_16x16x32_bf16(                     \
                                af[m], bf[n], acc[m][n], 0, 0, 0);                       \
        __builtin_amdgcn_s_setprio(0);                                                   \
        if (kt + 2 < 32) { asm volatile("s_waitcnt vmcnt(4)" ::: "memory"); }            \
        else             { asm volatile("s_waitcnt vmcnt(0)" ::: "memory"); }            \
        __builtin_amdgcn_sched_barrier(0);                                               \
        __builtin_amdgcn_s_barrier();   /* buf[cur^1] (tile kt+1) landed */              \
        __builtin_amdgcn_sched_barrier(0);                                               \
    }

// ---------------- GEMM1: [16384,3072] = x @ qkv_w^T, fused qkv epilogue ----------------
__global__ __launch_bounds__(512, 2) void k_gemm1_256(
    const u16* __restrict__ A,   // [16384][1024]
    const u16* __restrict__ Bw,  // [3072][1024]
    const float* __restrict__ bias, const float* __restrict__ pos_enc,
    u16* __restrict__ q, u16* __restrict__ kk_, u16* __restrict__ v)
{
    __shared__ u16 lds[32768];
    // bijective XCD swizzle: nwg = 12*64 = 768, %8==0
    const int lid = blockIdx.y * 12 + blockIdx.x;
    const int swz = (lid & 7) * 96 + (lid >> 3);
    const int bcol = (swz % 12) * 256;
    const int brow = (swz / 12) * 256;

    GEMM_PROLOGUE_AND_LOOP()

    // epilogue: C/D layout col=l&15, row=(l>>4)*4+j  [m89]
    const int part = bcol >> 10;                 // uniform per block (256 | 1024)
    u16* dst = (part == 0) ? q : (part == 1) ? kk_ : v;
    const int col_base = bcol + wc * 64 + fr;
    const int row_base = brow + wr * 128 + (l >> 4) * 4;
    #pragma unroll
    for (int n = 0; n < 4; ++n) {
        const int gc = col_base + n * 16;        // 0..3071
        const int c  = gc & 1023;
        float bv = bias[gc];
        if (part == 1) bv += pos_enc[c];
        const int h = c >> 6, d = c & 63;
        #pragma unroll
        for (int m = 0; m < 8; ++m)
            #pragma unroll
            for (int j = 0; j < 4; ++j) {
                const int gr = row_base + m * 16 + j;
                const int b_ = gr >> 12, i_ = gr & 4095;
                float val = acc[m][n][j] + bv;
                if (part != 2) val = fmaxf(val, 0.f);
                dst[(size_t)((b_ * NH + h) * NN + i_) * HDIM + d] = f2b(val);
            }
    }
}

// ---------------- GEMM2: [16384,1024] = out2 @ proj_w^T + b (fp32 out) ----------------
__global__ __launch_bounds__(512, 2) void k_gemm2_256(
    const u16* __restrict__ A,   // [16384][1024]
    const u16* __restrict__ Bw,  // [1024][1024]
    const float* __restrict__ bias, float* __restrict__ out)
{
    __shared__ u16 lds[32768];
    // bijective XCD swizzle: nwg = 4*64 = 256, %8==0
    const int lid = blockIdx.y * 4 + blockIdx.x;
    const int swz = (lid & 7) * 32 + (lid >> 3);
    const int bcol = (swz % 4) * 256;
    const int brow = (swz / 4) * 256;

    GEMM_PROLOGUE_AND_LOOP()

    const int col_base = bcol + wc * 64 + fr;
    const int row_base = brow + wr * 128 + (l >> 4) * 4;
    #pragma unroll
    for (int n = 0; n < 4; ++n) {
        const int gc = col_base + n * 16;
        const float bv = bias[gc];
        #pragma unroll
        for (int m = 0; m < 8; ++m)
            #pragma unroll
            for (int j = 0; j < 4; ++j) {
                const int gr = row_base + m * 16 + j;
                out[(size_t)gr * CDIM + gc] = acc[m][n][j] + bv;
            }
    }
}

// ---------------- K2: kv partials (bf16 in, fp32 out) ----------------
__global__ __launch_bounds__(256) void k_kv_partial(
    const u16* __restrict__ k, const u16* __restrict__ v,
    float* __restrict__ part_kv, float* __restrict__ part_ks)
{
    __shared__ float ks[32 * 64];
    __shared__ float vs[32 * 64];
    const int bh = blockIdx.x;
    const int chunk = blockIdx.y;
    const int t = threadIdx.x;
    const int cg = t >> 4;
    const int dg = t & 15;
    const int lr = t >> 3;               // 0..31
    const int lc = (t & 7) * 8;
    const size_t base = (size_t)bh * NN * HDIM + (size_t)chunk * 1024 * HDIM;
    float acc[4][4] = {};
    float ksac[4] = {};
    for (int j0 = 0; j0 < 1024; j0 += 32) {
        short8 kr = *reinterpret_cast<const short8*>(&k[base + (size_t)(j0 + lr) * 64 + lc]);
        short8 vr = *reinterpret_cast<const short8*>(&v[base + (size_t)(j0 + lr) * 64 + lc]);
        __syncthreads();
        #pragma unroll
        for (int j = 0; j < 8; ++j) {
            ks[lr * 64 + lc + j] = b2f(kr[j]);
            vs[lr * 64 + lc + j] = b2f(vr[j]);
        }
        __syncthreads();
        #pragma unroll
        for (int j = 0; j < 32; ++j) {
            float4 k4 = *reinterpret_cast<const float4*>(&ks[j * 64 + cg * 4]);
            float4 v4 = *reinterpret_cast<const float4*>(&vs[j * 64 + dg * 4]);
            const float* kp = reinterpret_cast<const float*>(&k4);
            const float* vp = reinterpret_cast<const float*>(&v4);
            #pragma unroll
            for (int ii = 0; ii < 4; ++ii) {
                ksac[ii] += kp[ii];
                #pragma unroll
                for (int jj = 0; jj < 4; ++jj)
                    acc[ii][jj] += kp[ii] * vp[jj];
            }
        }
    }
    const int pb = (chunk * BH + bh);
    #pragma unroll
    for (int ii = 0; ii < 4; ++ii) {
        #pragma unroll
        for (int jj = 0; jj < 4; ++jj)
            part_kv[pb * 4096 + (cg * 4 + ii) * 64 + dg * 4 + jj] = acc[ii][jj];
        if (dg == 0) part_ks[pb * 64 + cg * 4 + ii] = ksac[ii];
    }
}

// ---------------- K3: reduce partials -> kvt bf16 [80][64] per head ----------------
__global__ __launch_bounds__(256) void k_kv_reduce_t(
    const float* __restrict__ part_kv, const float* __restrict__ part_ks,
    u16* __restrict__ kvt)
{
    const int bh = blockIdx.x;
    const int t = threadIdx.x;
    u16* base = kvt + bh * 5120;          // 80*64
    #pragma unroll
    for (int r = 0; r < 16; ++r) {
        const int idx = r * 256 + t;       // idx = c*64 + d
        const int c = idx >> 6, d = idx & 63;
        float s = 0.f;
        #pragma unroll
        for (int ch = 0; ch < 4; ++ch) s += part_kv[(ch * BH + bh) * 4096 + idx];
        base[d * 64 + c] = f2b(s);         // transposed: row d, col c
    }
    if (t < 64) {
        float s = 0.f;
        #pragma unroll
        for (int ch = 0; ch < 4; ++ch) s += part_ks[(ch * BH + bh) * 64 + t];
        base[4096 + t] = f2b(s);           // row 64 = ksum
    }
    for (int z = t; z < 960; z += 256) base[4160 + z] = 0;   // rows 65..79 = 0
}

// ---------------- K4: MFMA attention finish + depthwise conv ----------------
__global__ __launch_bounds__(256) void k_attn_mfma(
    const u16* __restrict__ q, const u16* __restrict__ v,
    const u16* __restrict__ kvt,
    const float* __restrict__ dwc_w, const float* __restrict__ dwc_b,
    u16* __restrict__ out2)
{
    __shared__ u16 att[4][64 * 68];        // per-wave 64-token strip, stride 68 (bank-safe)
    const int t = threadIdx.x;
    const int l = t & 63, w = t >> 6;
    const int bh = blockIdx.x;
    const int tb = blockIdx.y * 256 + w * 64;     // token base of this wave
    const size_t hb = (size_t)bh * NN * HDIM;
    const u16* qb  = q + hb + (size_t)tb * HDIM;
    const u16* kvb = kvt + bh * 5120;

    const int fr = l & 15;
    const int kfrag = (l >> 4) * 8;

    short8 bfr[5][2];
    #pragma unroll
    for (int n = 0; n < 5; ++n)
        #pragma unroll
        for (int ks = 0; ks < 2; ++ks)
            bfr[n][ks] = *reinterpret_cast<const short8*>(&kvb[(n * 16 + fr) * 64 + ks * 32 + kfrag]);

    f32x4 acc[4][5];
    #pragma unroll
    for (int m = 0; m < 4; ++m)
        #pragma unroll
        for (int n = 0; n < 5; ++n) acc[m][n] = (f32x4){0.f, 0.f, 0.f, 0.f};

    #pragma unroll
    for (int m = 0; m < 4; ++m)
        #pragma unroll
        for (int ks = 0; ks < 2; ++ks) {
            short8 a = *reinterpret_cast<const short8*>(&qb[(m * 16 + fr) * 64 + ks * 32 + kfrag]);
            #pragma unroll
            for (int n = 0; n < 5; ++n)
                acc[m][n] = __builtin_amdgcn_mfma_f32_16x16x32_bf16(a, bfr[n][ks], acc[m][n], 0, 0, 0);
        }

    // epilogue: col = l&15, row = (l>>4)*4 + j; den = col 64 (n=4, lanes fr==0)
    #pragma unroll
    for (int m = 0; m < 4; ++m)
        #pragma unroll
        for (int j = 0; j < 4; ++j) {
            const float den = __shfl(acc[m][4][j], l & 48);
            const float z = 1.f / (den + 1e-6f);
            const int row = m * 16 + (l >> 4) * 4 + j;
            #pragma unroll
            for (int n = 0; n < 4; ++n)
                att[w][row * 68 + fr + n * 16] = f2b(acc[m][n][j] * z);
        }
    __syncthreads();

    // phase 2: lane = d column; rolling 5-tap conv along tokens; coalesced store
    const int d = l;
    float w5[5];
    #pragma unroll
    for (int dh = 0; dh < 5; ++dh) w5[dh] = dwc_w[d * 25 + dh * 5 + 2];  // kernel col 2 only
    const float cbias = dwc_b[d];
    const int b_ = bh >> 4, h_ = bh & 15;
    u16* obase = out2 + (size_t)b_ * NN * CDIM + (size_t)h_ * 64 + d;
    float win[5];
    #pragma unroll
    for (int p = 0; p < 4; ++p) {
        const int src = tb - 2 + p;
        win[p] = (src >= 0 && src < NN) ? b2f(v[hb + (size_t)src * 64 + d]) : 0.f;
    }
    for (int it = 0; it < 64; ++it) {
        const int srcn = tb + it + 2;
        win[4] = (srcn < NN) ? b2f(v[hb + (size_t)srcn * 64 + d]) : 0.f;
        const float fm = cbias + w5[0] * win[0] + w5[1] * win[1] + w5[2] * win[2]
                               + w5[3] * win[3] + w5[4] * win[4];
        const float attn = b2f((short)att[w][it * 68 + d]);
        obase[(size_t)(tb + it) * CDIM] = f2b(attn + fm);
        win[0] = win[1]; win[1] = win[2]; win[2] = win[3]; win[3] = win[4];
    }
}

extern "C" void kernel_launch(void* const* d_in, const int* in_sizes, int n_in,
                              void* d_out, int out_size, void* d_ws, size_t ws_size,
                              hipStream_t stream)
{
    const float* x       = (const float*)d_in[0];
    const float* qkv_w   = (const float*)d_in[1];
    const float* qkv_b   = (const float*)d_in[2];
    const float* proj_w  = (const float*)d_in[3];
    const float* proj_b  = (const float*)d_in[4];
    const float* pos_enc = (const float*)d_in[5];
    const float* dwc_w   = (const float*)d_in[6];
    const float* dwc_b   = (const float*)d_in[7];

    const size_t QKV = 16777216;                       // elements per q/k/v plane
    char* p = (char*)d_ws;
    u16* q_b    = (u16*)p;               p += QKV * 2;
    u16* k_b    = (u16*)p;               p += QKV * 2;  // reused as out2 bf16
    u16* v_b    = (u16*)p;               p += QKV * 2;
    u16* x_b    = (u16*)p;               p += QKV * 2;
    u16* qkvw_b = (u16*)p;               p += (size_t)3145728 * 2;
    u16* projw_b= (u16*)p;               p += (size_t)1048576 * 2;
    float* part_kv = (float*)p;          p += (size_t)1048576 * 4;
    float* part_ks = (float*)p;          p += (size_t)16384 * 4;
    u16* kvt       = (u16*)p;            p += (size_t)(64 * 5120) * 2;
    const size_t need_bytes = (size_t)(p - (char*)d_ws);

    if (ws_size < need_bytes) {
        const float diag = 4096.0f + (float)(ws_size >> 20);
        k_fill_diag<<<(out_size + 255) / 256, 256, 0, stream>>>((float*)d_out, out_size, diag);
        return;
    }

    u16* out2 = k_b;
    float* out = (float*)d_out;

    k_f32_to_bf16<<<16384, 256, 0, stream>>>(x,      x_b,     4194304);
    k_f32_to_bf16<<< 3072, 256, 0, stream>>>(qkv_w,  qkvw_b,   786432);
    k_f32_to_bf16<<< 1024, 256, 0, stream>>>(proj_w, projw_b,  262144);

    k_gemm1_256  <<<dim3(12, 64), 512, 0, stream>>>(x_b, qkvw_b, qkv_b, pos_enc, q_b, k_b, v_b);
    k_kv_partial <<<dim3(64, 4),  256, 0, stream>>>(k_b, v_b, part_kv, part_ks);
    k_kv_reduce_t<<<64,           256, 0, stream>>>(part_kv, part_ks, kvt);
    k_attn_mfma  <<<dim3(64, 16), 256, 0, stream>>>(q_b, v_b, kvt, dwc_w, dwc_b, out2);
    k_gemm2_256  <<<dim3(4, 64),  512, 0, stream>>>(out2, projw_b, proj_b, out);
}

// Round 6
// 312.786 us; speedup vs baseline: 6.4080x; 1.0084x over previous
//
#include <hip/hip_runtime.h>

// SLabLinearAttention: B=4 N=4096 C=1024 H=16 HD=64 KH=5
// Round 6: full 8-phase GEMM schedule (T3+T4+T2+T5): BM=BN=256, BK=64, 8 waves,
// 128KB LDS dbuf split into k-half regions; per K-tile 4 phases of
// {ds_read || half-tile stage || 16 MFMA}; vmcnt(4) once per K-tile (never 0
// mid-loop); LDS XOR-swizzle both-sides (verified 0-conflict in R5); setprio
// around MFMA clusters. Attention stages unchanged from R5.

#define BB   4
#define NN   4096
#define CDIM 1024
#define NH   16
#define HDIM 64
#define BH   64

typedef __attribute__((ext_vector_type(8))) short short8;
typedef __attribute__((ext_vector_type(4))) float f32x4;
typedef unsigned short u16;

__device__ __forceinline__ float b2f(short s) {
    union { unsigned u; float f; } c;
    c.u = ((unsigned)(unsigned short)s) << 16;
    return c.f;
}
__device__ __forceinline__ u16 f2b(float f) {   // RNE
    unsigned u = __float_as_uint(f);
    return (u16)((u + 0x7fffu + ((u >> 16) & 1u)) >> 16);
}
__device__ __forceinline__ void gload16(const void* g, void* l) {
    __builtin_amdgcn_global_load_lds((const __attribute__((address_space(1))) void*)g,
                                     (__attribute__((address_space(3))) void*)l, 16, 0, 0);
}

__global__ __launch_bounds__(256) void k_fill_diag(float* __restrict__ out, int n, float val)
{
    int i = blockIdx.x * 256 + threadIdx.x;
    if (i < n) out[i] = val;
}

__global__ __launch_bounds__(256) void k_f32_to_bf16(const float* __restrict__ in,
                                                     u16* __restrict__ out, int n4)
{
    int i = blockIdx.x * 256 + threadIdx.x;
    if (i < n4) {
        float4 v = reinterpret_cast<const float4*>(in)[i];
        ushort4 o;
        o.x = f2b(v.x); o.y = f2b(v.y); o.z = f2b(v.z); o.w = f2b(v.w);
        reinterpret_cast<ushort4*>(out)[i] = o;
    }
}

// ================= 8-phase 256x256 BK=64 GEMM core =================
// LDS (u16 elems): buf b @ b*32768; A region @ +0 (kh*8192), B region @ +16384 (kh*8192).
// Region = [256 rows][32 k-elems]; row = 64B = 4 x 16B chunks; phys chunk = chunk ^ ((row>>1)&3)
// (both-sides involution: pre-swizzled global source for linear gload_lds dest, swizzled ds_read).
// Staging ledger per iter kt: P0->A_kh1(kt+1), P1->B_kh1(kt+1), P2->A_kh0(kt+2), P3->B_kh0(kt+2).
// vmcnt(4) at each K-tile boundary confirms kt+1 landed, leaves kt+2's kh0 pair in flight.
#define GEMM256_8PH()                                                                    \
    const int t = threadIdx.x;                                                           \
    const int l = t & 63, w = t >> 6;                                                    \
    const int wr = w >> 2, wc = w & 3;                                                   \
    const int fr = l & 15;                                                               \
    const int physE  = ((l >> 4) ^ ((fr >> 1) & 3)) * 8;                                 \
    const int qa     = ((l & 3) ^ ((l >> 3) & 3)) * 8;                                   \
    const int aRow   = w * 16 + (l >> 2);                                                \
    const u16* gA0 = A  + (size_t)(brow + aRow) * 1024 + qa;                             \
    const u16* gB0 = Bw + (size_t)(bcol + aRow) * 1024 + qa;                             \
    char* ldsc = (char*)lds;                                                             \
    const int afBase = (wr * 128 + fr) * 32 + physE;                                     \
    const int bfBase = 16384 + (wc * 64 + fr) * 32 + physE;                              \
    f32x4 acc[8][4];                                                                     \
    _Pragma("unroll")                                                                    \
    for (int m = 0; m < 8; ++m)                                                          \
        _Pragma("unroll")                                                                \
        for (int n = 0; n < 4; ++n) acc[m][n] = (f32x4){0.f, 0.f, 0.f, 0.f};             \
    auto STG = [&](int kt, int kh, int isB) {                                            \
        const u16* g = (isB ? gB0 : gA0) + kt * 64 + kh * 32;                            \
        char* d = ldsc + (kt & 1) * 65536 + isB * 32768 + kh * 16384 + w * 1024 + l * 16;\
        gload16(g,          d);                                                          \
        gload16(g + 131072, d + 8192);                                                   \
    };                                                                                   \
    STG(0,0,0); STG(0,0,1); STG(0,1,0); STG(0,1,1); STG(1,0,0); STG(1,0,1);              \
    asm volatile("s_waitcnt vmcnt(4)" ::: "memory");                                     \
    __builtin_amdgcn_sched_barrier(0);                                                   \
    __builtin_amdgcn_s_barrier();                                                        \
    __builtin_amdgcn_sched_barrier(0);                                                   \
    _Pragma("unroll 1")                                                                  \
    for (int kt = 0; kt < 16; ++kt) {                                                    \
        const int B0 = (kt & 1) * 32768;                                                 \
        short8 af[4], bf[4];                                                             \
        /* phase 0: (m0-3, ks0) */                                                       \
        _Pragma("unroll")                                                                \
        for (int m = 0; m < 4; ++m)                                                      \
            af[m] = *reinterpret_cast<const short8*>(&lds[B0 + afBase + m * 512]);       \
        _Pragma("unroll")                                                                \
        for (int n = 0; n < 4; ++n)                                                      \
            bf[n] = *reinterpret_cast<const short8*>(&lds[B0 + bfBase + n * 512]);       \
        if (kt + 1 < 16) STG(kt + 1, 1, 0);                                              \
        __builtin_amdgcn_sched_barrier(0);                                               \
        __builtin_amdgcn_s_barrier();                                                    \
        asm volatile("s_waitcnt lgkmcnt(0)" ::: "memory");                               \
        __builtin_amdgcn_sched_barrier(0);                                               \
        __builtin_amdgcn_s_setprio(1);                                                   \
        _Pragma("unroll")                                                                \
        for (int m = 0; m < 4; ++m)                                                      \
            _Pragma("unroll")                                                            \
            for (int n = 0; n < 4; ++n)                                                  \
                acc[m][n] = __builtin_amdgcn_mfma_f32_16x16x32_bf16(af[m], bf[n], acc[m][n], 0, 0, 0); \
        __builtin_amdgcn_s_setprio(0);                                                   \
        __builtin_amdgcn_sched_barrier(0);                                               \
        __builtin_amdgcn_s_barrier();                                                    \
        __builtin_amdgcn_sched_barrier(0);                                               \
        /* phase 1: (m4-7, ks0) */                                                       \
        _Pragma("unroll")                                                                \
        for (int m = 0; m < 4; ++m)                                                      \
            af[m] = *reinterpret_cast<const short8*>(&lds[B0 + afBase + (m + 4) * 512]); \
        if (kt + 1 < 16) STG(kt + 1, 1, 1);                                              \
        __builtin_amdgcn_sched_barrier(0);                                               \
        __builtin_amdgcn_s_barrier();                                                    \
        asm volatile("s_waitcnt lgkmcnt(0)" ::: "memory");                               \
        __builtin_amdgcn_sched_barrier(0);                                               \
        __builtin_amdgcn_s_setprio(1);                                                   \
        _Pragma("unroll")                                                                \
        for (int m = 0; m < 4; ++m)                                                      \
            _Pragma("unroll")                                                            \
            for (int n = 0; n < 4; ++n)                                                  \
                acc[m + 4][n] = __builtin_amdgcn_mfma_f32_16x16x32_bf16(af[m], bf[n], acc[m + 4][n], 0, 0, 0); \
        __builtin_amdgcn_s_setprio(0);                                                   \
        __builtin_amdgcn_sched_barrier(0);                                               \
        __builtin_amdgcn_s_barrier();                                                    \
        __builtin_amdgcn_sched_barrier(0);                                               \
        /* phase 2: (m0-3, ks1) */                                                       \
        _Pragma("unroll")                                                                \
        for (int m = 0; m < 4; ++m)                                                      \
            af[m] = *reinterpret_cast<const short8*>(&lds[B0 + 8192 + afBase + m * 512]);\
        _Pragma("unroll")                                                                \
        for (int n = 0; n < 4; ++n)                                                      \
            bf[n] = *reinterpret_cast<const short8*>(&lds[B0 + 8192 + bfBase + n * 512]);\
        if (kt + 2 < 16) STG(kt + 2, 0, 0);                                              \
        __builtin_amdgcn_sched_barrier(0);                                               \
        __builtin_amdgcn_s_barrier();                                                    \
        asm volatile("s_waitcnt lgkmcnt(0)" ::: "memory");                               \
        __builtin_amdgcn_sched_barrier(0);                                               \
        __builtin_amdgcn_s_setprio(1);                                                   \
        _Pragma("unroll")                                                                \
        for (int m = 0; m < 4; ++m)                                                      \
            _Pragma("unroll")                                                            \
            for (int n = 0; n < 4; ++n)                                                  \
                acc[m][n] = __builtin_amdgcn_mfma_f32_16x16x32_bf16(af[m], bf[n], acc[m][n], 0, 0, 0); \
        __builtin_amdgcn_s_setprio(0);                                                   \
        __builtin_amdgcn_sched_barrier(0);                                               \
        __builtin_amdgcn_s_barrier();                                                    \
        __builtin_amdgcn_sched_barrier(0);                                               \
        /* phase 3: (m4-7, ks1) */                                                       \
        _Pragma("unroll")                                                                \
        for (int m = 0; m < 4; ++m)                                                      \
            af[m] = *reinterpret_cast<const short8*>(&lds[B0 + 8192 + afBase + (m + 4) * 512]); \
        if (kt + 2 < 16) STG(kt + 2, 0, 1);                                              \
        __builtin_amdgcn_sched_barrier(0);                                               \
        __builtin_amdgcn_s_barrier();                                                    \
        asm volatile("s_waitcnt lgkmcnt(0)" ::: "memory");                               \
        __builtin_amdgcn_sched_barrier(0);                                               \
        __builtin_amdgcn_s_setprio(1);                                                   \
        _Pragma("unroll")                                                                \
        for (int m = 0; m < 4; ++m)                                                      \
            _Pragma("unroll")                                                            \
            for (int n = 0; n < 4; ++n)                                                  \
                acc[m + 4][n] = __builtin_amdgcn_mfma_f32_16x16x32_bf16(af[m], bf[n], acc[m + 4][n], 0, 0, 0); \
        __builtin_amdgcn_s_setprio(0);                                                   \
        __builtin_amdgcn_sched_barrier(0);                                               \
        if (kt < 15) { asm volatile("s_waitcnt vmcnt(4)" ::: "memory"); }                \
        else         { asm volatile("s_waitcnt vmcnt(0)" ::: "memory"); }                \
        __builtin_amdgcn_sched_barrier(0);                                               \
        __builtin_amdgcn_s_barrier();                                                    \
        __builtin_amdgcn_sched_barrier(0);                                               \
    }

// ---------------- GEMM1: [16384,3072] = x @ qkv_w^T, fused qkv epilogue ----------------
__global__ __launch_bounds__(512, 2) void k_gemm1_256(
    const u16* __restrict__ A,   // [16384][1024]
    const u16* __restrict__ Bw,  // [3072][1024]
    const float* __restrict__ bias, const float* __restrict__ pos_enc,
    u16* __restrict__ q, u16* __restrict__ kk_, u16* __restrict__ v)
{
    __shared__ u16 lds[65536];   // 128 KiB
    // bijective XCD swizzle: nwg = 12*64 = 768, %8==0
    const int lid = blockIdx.y * 12 + blockIdx.x;
    const int swz = (lid & 7) * 96 + (lid >> 3);
    const int bcol = (swz % 12) * 256;
    const int brow = (swz / 12) * 256;

    GEMM256_8PH()

    // epilogue: C/D layout col=l&15, row=(l>>4)*4+j  [m89]
    const int part = bcol >> 10;                 // uniform per block (256 | 1024)
    u16* dst = (part == 0) ? q : (part == 1) ? kk_ : v;
    const int col_base = bcol + wc * 64 + fr;
    const int row_base = brow + wr * 128 + (l >> 4) * 4;
    #pragma unroll
    for (int n = 0; n < 4; ++n) {
        const int gc = col_base + n * 16;        // 0..3071
        const int c  = gc & 1023;
        float bv = bias[gc];
        if (part == 1) bv += pos_enc[c];
        const int h = c >> 6, d = c & 63;
        #pragma unroll
        for (int m = 0; m < 8; ++m)
            #pragma unroll
            for (int j = 0; j < 4; ++j) {
                const int gr = row_base + m * 16 + j;
                const int b_ = gr >> 12, i_ = gr & 4095;
                float val = acc[m][n][j] + bv;
                if (part != 2) val = fmaxf(val, 0.f);
                dst[(size_t)((b_ * NH + h) * NN + i_) * HDIM + d] = f2b(val);
            }
    }
}

// ---------------- GEMM2: [16384,1024] = out2 @ proj_w^T + b (fp32 out) ----------------
__global__ __launch_bounds__(512, 2) void k_gemm2_256(
    const u16* __restrict__ A,   // [16384][1024]
    const u16* __restrict__ Bw,  // [1024][1024]
    const float* __restrict__ bias, float* __restrict__ out)
{
    __shared__ u16 lds[65536];   // 128 KiB
    // bijective XCD swizzle: nwg = 4*64 = 256, %8==0
    const int lid = blockIdx.y * 4 + blockIdx.x;
    const int swz = (lid & 7) * 32 + (lid >> 3);
    const int bcol = (swz % 4) * 256;
    const int brow = (swz / 4) * 256;

    GEMM256_8PH()

    const int col_base = bcol + wc * 64 + fr;
    const int row_base = brow + wr * 128 + (l >> 4) * 4;
    #pragma unroll
    for (int n = 0; n < 4; ++n) {
        const int gc = col_base + n * 16;
        const float bv = bias[gc];
        #pragma unroll
        for (int m = 0; m < 8; ++m)
            #pragma unroll
            for (int j = 0; j < 4; ++j) {
                const int gr = row_base + m * 16 + j;
                out[(size_t)gr * CDIM + gc] = acc[m][n][j] + bv;
            }
    }
}

// ---------------- K2: kv partials (bf16 in, fp32 out) ----------------
__global__ __launch_bounds__(256) void k_kv_partial(
    const u16* __restrict__ k, const u16* __restrict__ v,
    float* __restrict__ part_kv, float* __restrict__ part_ks)
{
    __shared__ float ks[32 * 64];
    __shared__ float vs[32 * 64];
    const int bh = blockIdx.x;
    const int chunk = blockIdx.y;
    const int t = threadIdx.x;
    const int cg = t >> 4;
    const int dg = t & 15;
    const int lr = t >> 3;               // 0..31
    const int lc = (t & 7) * 8;
    const size_t base = (size_t)bh * NN * HDIM + (size_t)chunk * 1024 * HDIM;
    float acc[4][4] = {};
    float ksac[4] = {};
    for (int j0 = 0; j0 < 1024; j0 += 32) {
        short8 kr = *reinterpret_cast<const short8*>(&k[base + (size_t)(j0 + lr) * 64 + lc]);
        short8 vr = *reinterpret_cast<const short8*>(&v[base + (size_t)(j0 + lr) * 64 + lc]);
        __syncthreads();
        #pragma unroll
        for (int j = 0; j < 8; ++j) {
            ks[lr * 64 + lc + j] = b2f(kr[j]);
            vs[lr * 64 + lc + j] = b2f(vr[j]);
        }
        __syncthreads();
        #pragma unroll
        for (int j = 0; j < 32; ++j) {
            float4 k4 = *reinterpret_cast<const float4*>(&ks[j * 64 + cg * 4]);
            float4 v4 = *reinterpret_cast<const float4*>(&vs[j * 64 + dg * 4]);
            const float* kp = reinterpret_cast<const float*>(&k4);
            const float* vp = reinterpret_cast<const float*>(&v4);
            #pragma unroll
            for (int ii = 0; ii < 4; ++ii) {
                ksac[ii] += kp[ii];
                #pragma unroll
                for (int jj = 0; jj < 4; ++jj)
                    acc[ii][jj] += kp[ii] * vp[jj];
            }
        }
    }
    const int pb = (chunk * BH + bh);
    #pragma unroll
    for (int ii = 0; ii < 4; ++ii) {
        #pragma unroll
        for (int jj = 0; jj < 4; ++jj)
            part_kv[pb * 4096 + (cg * 4 + ii) * 64 + dg * 4 + jj] = acc[ii][jj];
        if (dg == 0) part_ks[pb * 64 + cg * 4 + ii] = ksac[ii];
    }
}

// ---------------- K3: reduce partials -> kvt bf16 [80][64] per head ----------------
__global__ __launch_bounds__(256) void k_kv_reduce_t(
    const float* __restrict__ part_kv, const float* __restrict__ part_ks,
    u16* __restrict__ kvt)
{
    const int bh = blockIdx.x;
    const int t = threadIdx.x;
    u16* base = kvt + bh * 5120;          // 80*64
    #pragma unroll
    for (int r = 0; r < 16; ++r) {
        const int idx = r * 256 + t;       // idx = c*64 + d
        const int c = idx >> 6, d = idx & 63;
        float s = 0.f;
        #pragma unroll
        for (int ch = 0; ch < 4; ++ch) s += part_kv[(ch * BH + bh) * 4096 + idx];
        base[d * 64 + c] = f2b(s);         // transposed: row d, col c
    }
    if (t < 64) {
        float s = 0.f;
        #pragma unroll
        for (int ch = 0; ch < 4; ++ch) s += part_ks[(ch * BH + bh) * 64 + t];
        base[4096 + t] = f2b(s);           // row 64 = ksum
    }
    for (int z = t; z < 960; z += 256) base[4160 + z] = 0;   // rows 65..79 = 0
}

// ---------------- K4: MFMA attention finish + depthwise conv ----------------
__global__ __launch_bounds__(256) void k_attn_mfma(
    const u16* __restrict__ q, const u16* __restrict__ v,
    const u16* __restrict__ kvt,
    const float* __restrict__ dwc_w, const float* __restrict__ dwc_b,
    u16* __restrict__ out2)
{
    __shared__ u16 att[4][64 * 68];        // per-wave 64-token strip, stride 68 (bank-safe)
    const int t = threadIdx.x;
    const int l = t & 63, w = t >> 6;
    const int bh = blockIdx.x;
    const int tb = blockIdx.y * 256 + w * 64;     // token base of this wave
    const size_t hb = (size_t)bh * NN * HDIM;
    const u16* qb  = q + hb + (size_t)tb * HDIM;
    const u16* kvb = kvt + bh * 5120;

    const int fr = l & 15;
    const int kfrag = (l >> 4) * 8;

    short8 bfr[5][2];
    #pragma unroll
    for (int n = 0; n < 5; ++n)
        #pragma unroll
        for (int ks = 0; ks < 2; ++ks)
            bfr[n][ks] = *reinterpret_cast<const short8*>(&kvb[(n * 16 + fr) * 64 + ks * 32 + kfrag]);

    f32x4 acc[4][5];
    #pragma unroll
    for (int m = 0; m < 4; ++m)
        #pragma unroll
        for (int n = 0; n < 5; ++n) acc[m][n] = (f32x4){0.f, 0.f, 0.f, 0.f};

    #pragma unroll
    for (int m = 0; m < 4; ++m)
        #pragma unroll
        for (int ks = 0; ks < 2; ++ks) {
            short8 a = *reinterpret_cast<const short8*>(&qb[(m * 16 + fr) * 64 + ks * 32 + kfrag]);
            #pragma unroll
            for (int n = 0; n < 5; ++n)
                acc[m][n] = __builtin_amdgcn_mfma_f32_16x16x32_bf16(a, bfr[n][ks], acc[m][n], 0, 0, 0);
        }

    // epilogue: col = l&15, row = (l>>4)*4 + j; den = col 64 (n=4, lanes fr==0)
    #pragma unroll
    for (int m = 0; m < 4; ++m)
        #pragma unroll
        for (int j = 0; j < 4; ++j) {
            const float den = __shfl(acc[m][4][j], l & 48);
            const float z = 1.f / (den + 1e-6f);
            const int row = m * 16 + (l >> 4) * 4 + j;
            #pragma unroll
            for (int n = 0; n < 4; ++n)
                att[w][row * 68 + fr + n * 16] = f2b(acc[m][n][j] * z);
        }
    __syncthreads();

    // phase 2: lane = d column; rolling 5-tap conv along tokens; coalesced store
    const int d = l;
    float w5[5];
    #pragma unroll
    for (int dh = 0; dh < 5; ++dh) w5[dh] = dwc_w[d * 25 + dh * 5 + 2];  // kernel col 2 only
    const float cbias = dwc_b[d];
    const int b_ = bh >> 4, h_ = bh & 15;
    u16* obase = out2 + (size_t)b_ * NN * CDIM + (size_t)h_ * 64 + d;
    float win[5];
    #pragma unroll
    for (int p = 0; p < 4; ++p) {
        const int src = tb - 2 + p;
        win[p] = (src >= 0 && src < NN) ? b2f(v[hb + (size_t)src * 64 + d]) : 0.f;
    }
    for (int it = 0; it < 64; ++it) {
        const int srcn = tb + it + 2;
        win[4] = (srcn < NN) ? b2f(v[hb + (size_t)srcn * 64 + d]) : 0.f;
        const float fm = cbias + w5[0] * win[0] + w5[1] * win[1] + w5[2] * win[2]
                               + w5[3] * win[3] + w5[4] * win[4];
        const float attn = b2f((short)att[w][it * 68 + d]);
        obase[(size_t)(tb + it) * CDIM] = f2b(attn + fm);
        win[0] = win[1]; win[1] = win[2]; win[2] = win[3]; win[3] = win[4];
    }
}

extern "C" void kernel_launch(void* const* d_in, const int* in_sizes, int n_in,
                              void* d_out, int out_size, void* d_ws, size_t ws_size,
                              hipStream_t stream)
{
    const float* x       = (const float*)d_in[0];
    const float* qkv_w   = (const float*)d_in[1];
    const float* qkv_b   = (const float*)d_in[2];
    const float* proj_w  = (const float*)d_in[3];
    const float* proj_b  = (const float*)d_in[4];
    const float* pos_enc = (const float*)d_in[5];
    const float* dwc_w   = (const float*)d_in[6];
    const float* dwc_b   = (const float*)d_in[7];

    const size_t QKV = 16777216;                       // elements per q/k/v plane
    char* p = (char*)d_ws;
    u16* q_b    = (u16*)p;               p += QKV * 2;
    u16* k_b    = (u16*)p;               p += QKV * 2;  // reused as out2 bf16
    u16* v_b    = (u16*)p;               p += QKV * 2;
    u16* x_b    = (u16*)p;               p += QKV * 2;
    u16* qkvw_b = (u16*)p;               p += (size_t)3145728 * 2;
    u16* projw_b= (u16*)p;               p += (size_t)1048576 * 2;
    float* part_kv = (float*)p;          p += (size_t)1048576 * 4;
    float* part_ks = (float*)p;          p += (size_t)16384 * 4;
    u16* kvt       = (u16*)p;            p += (size_t)(64 * 5120) * 2;
    const size_t need_bytes = (size_t)(p - (char*)d_ws);

    if (ws_size < need_bytes) {
        const float diag = 4096.0f + (float)(ws_size >> 20);
        k_fill_diag<<<(out_size + 255) / 256, 256, 0, stream>>>((float*)d_out, out_size, diag);
        return;
    }

    u16* out2 = k_b;
    float* out = (float*)d_out;

    k_f32_to_bf16<<<16384, 256, 0, stream>>>(x,      x_b,     4194304);
    k_f32_to_bf16<<< 3072, 256, 0, stream>>>(qkv_w,  qkvw_b,   786432);
    k_f32_to_bf16<<< 1024, 256, 0, stream>>>(proj_w, projw_b,  262144);

    k_gemm1_256  <<<dim3(12, 64), 512, 0, stream>>>(x_b, qkvw_b, qkv_b, pos_enc, q_b, k_b, v_b);
    k_kv_partial <<<dim3(64, 4),  256, 0, stream>>>(k_b, v_b, part_kv, part_ks);
    k_kv_reduce_t<<<64,           256, 0, stream>>>(part_kv, part_ks, kvt);
    k_attn_mfma  <<<dim3(64, 16), 256, 0, stream>>>(q_b, v_b, kvt, dwc_w, dwc_b, out2);
    k_gemm2_256  <<<dim3(4, 64),  512, 0, stream>>>(out2, projw_b, proj_b, out);
}

// Round 7
// 286.125 us; speedup vs baseline: 7.0051x; 1.0932x over previous
//
#include <hip/hip_runtime.h>

// SLabLinearAttention: B=4 N=4096 C=1024 H=16 HD=64 KH=5
// Round 7: (a) gemm1 LDS-staged coalesced epilogue (kills 1.9x write amplification;
//              also emits TRANSPOSED kt_g[c][j], vt_g[d][j] copies),
//          (b) kv stage via MFMA reading kt_g/vt_g rows (no LDS transpose at all).
// K-loop (8-phase, swizzled, counted vmcnt) unchanged from R6.

#define BB   4
#define NN   4096
#define CDIM 1024
#define NH   16
#define HDIM 64
#define BH   64

typedef __attribute__((ext_vector_type(8))) short short8;
typedef __attribute__((ext_vector_type(4))) float f32x4;
typedef unsigned short u16;

__device__ __forceinline__ float b2f(short s) {
    union { unsigned u; float f; } c;
    c.u = ((unsigned)(unsigned short)s) << 16;
    return c.f;
}
__device__ __forceinline__ u16 f2b(float f) {   // RNE
    unsigned u = __float_as_uint(f);
    return (u16)((u + 0x7fffu + ((u >> 16) & 1u)) >> 16);
}
__device__ __forceinline__ void gload16(const void* g, void* l) {
    __builtin_amdgcn_global_load_lds((const __attribute__((address_space(1))) void*)g,
                                     (__attribute__((address_space(3))) void*)l, 16, 0, 0);
}

__global__ __launch_bounds__(256) void k_fill_diag(float* __restrict__ out, int n, float val)
{
    int i = blockIdx.x * 256 + threadIdx.x;
    if (i < n) out[i] = val;
}

__global__ __launch_bounds__(256) void k_f32_to_bf16(const float* __restrict__ in,
                                                     u16* __restrict__ out, int n4)
{
    int i = blockIdx.x * 256 + threadIdx.x;
    if (i < n4) {
        float4 v = reinterpret_cast<const float4*>(in)[i];
        ushort4 o;
        o.x = f2b(v.x); o.y = f2b(v.y); o.z = f2b(v.z); o.w = f2b(v.w);
        reinterpret_cast<ushort4*>(out)[i] = o;
    }
}

// ================= 8-phase 256x256 BK=64 GEMM core (unchanged from R6) =================
#define GEMM256_8PH()                                                                    \
    const int t = threadIdx.x;                                                           \
    const int l = t & 63, w = t >> 6;                                                    \
    const int wr = w >> 2, wc = w & 3;                                                   \
    const int fr = l & 15;                                                               \
    const int physE  = ((l >> 4) ^ ((fr >> 1) & 3)) * 8;                                 \
    const int qa     = ((l & 3) ^ ((l >> 3) & 3)) * 8;                                   \
    const int aRow   = w * 16 + (l >> 2);                                                \
    const u16* gA0 = A  + (size_t)(brow + aRow) * 1024 + qa;                             \
    const u16* gB0 = Bw + (size_t)(bcol + aRow) * 1024 + qa;                             \
    char* ldsc = (char*)lds;                                                             \
    const int afBase = (wr * 128 + fr) * 32 + physE;                                     \
    const int bfBase = 16384 + (wc * 64 + fr) * 32 + physE;                              \
    f32x4 acc[8][4];                                                                     \
    _Pragma("unroll")                                                                    \
    for (int m = 0; m < 8; ++m)                                                          \
        _Pragma("unroll")                                                                \
        for (int n = 0; n < 4; ++n) acc[m][n] = (f32x4){0.f, 0.f, 0.f, 0.f};             \
    auto STG = [&](int kt, int kh, int isB) {                                            \
        const u16* g = (isB ? gB0 : gA0) + kt * 64 + kh * 32;                            \
        char* d = ldsc + (kt & 1) * 65536 + isB * 32768 + kh * 16384 + w * 1024 + l * 16;\
        gload16(g,          d);                                                          \
        gload16(g + 131072, d + 8192);                                                   \
    };                                                                                   \
    STG(0,0,0); STG(0,0,1); STG(0,1,0); STG(0,1,1); STG(1,0,0); STG(1,0,1);              \
    asm volatile("s_waitcnt vmcnt(4)" ::: "memory");                                     \
    __builtin_amdgcn_sched_barrier(0);                                                   \
    __builtin_amdgcn_s_barrier();                                                        \
    __builtin_amdgcn_sched_barrier(0);                                                   \
    _Pragma("unroll 1")                                                                  \
    for (int kt = 0; kt < 16; ++kt) {                                                    \
        const int B0 = (kt & 1) * 32768;                                                 \
        short8 af[4], bf[4];                                                             \
        _Pragma("unroll")                                                                \
        for (int m = 0; m < 4; ++m)                                                      \
            af[m] = *reinterpret_cast<const short8*>(&lds[B0 + afBase + m * 512]);       \
        _Pragma("unroll")                                                                \
        for (int n = 0; n < 4; ++n)                                                      \
            bf[n] = *reinterpret_cast<const short8*>(&lds[B0 + bfBase + n * 512]);       \
        if (kt + 1 < 16) STG(kt + 1, 1, 0);                                              \
        __builtin_amdgcn_sched_barrier(0);                                               \
        __builtin_amdgcn_s_barrier();                                                    \
        asm volatile("s_waitcnt lgkmcnt(0)" ::: "memory");                               \
        __builtin_amdgcn_sched_barrier(0);                                               \
        __builtin_amdgcn_s_setprio(1);                                                   \
        _Pragma("unroll")                                                                \
        for (int m = 0; m < 4; ++m)                                                      \
            _Pragma("unroll")                                                            \
            for (int n = 0; n < 4; ++n)                                                  \
                acc[m][n] = __builtin_amdgcn_mfma_f32_16x16x32_bf16(af[m], bf[n], acc[m][n], 0, 0, 0); \
        __builtin_amdgcn_s_setprio(0);                                                   \
        __builtin_amdgcn_sched_barrier(0);                                               \
        __builtin_amdgcn_s_barrier();                                                    \
        __builtin_amdgcn_sched_barrier(0);                                               \
        _Pragma("unroll")                                                                \
        for (int m = 0; m < 4; ++m)                                                      \
            af[m] = *reinterpret_cast<const short8*>(&lds[B0 + afBase + (m + 4) * 512]); \
        if (kt + 1 < 16) STG(kt + 1, 1, 1);                                              \
        __builtin_amdgcn_sched_barrier(0);                                               \
        __builtin_amdgcn_s_barrier();                                                    \
        asm volatile("s_waitcnt lgkmcnt(0)" ::: "memory");                               \
        __builtin_amdgcn_sched_barrier(0);                                               \
        __builtin_amdgcn_s_setprio(1);                                                   \
        _Pragma("unroll")                                                                \
        for (int m = 0; m < 4; ++m)                                                      \
            _Pragma("unroll")                                                            \
            for (int n = 0; n < 4; ++n)                                                  \
                acc[m + 4][n] = __builtin_amdgcn_mfma_f32_16x16x32_bf16(af[m], bf[n], acc[m + 4][n], 0, 0, 0); \
        __builtin_amdgcn_s_setprio(0);                                                   \
        __builtin_amdgcn_sched_barrier(0);                                               \
        __builtin_amdgcn_s_barrier();                                                    \
        __builtin_amdgcn_sched_barrier(0);                                               \
        _Pragma("unroll")                                                                \
        for (int m = 0; m < 4; ++m)                                                      \
            af[m] = *reinterpret_cast<const short8*>(&lds[B0 + 8192 + afBase + m * 512]);\
        _Pragma("unroll")                                                                \
        for (int n = 0; n < 4; ++n)                                                      \
            bf[n] = *reinterpret_cast<const short8*>(&lds[B0 + 8192 + bfBase + n * 512]);\
        if (kt + 2 < 16) STG(kt + 2, 0, 0);                                              \
        __builtin_amdgcn_sched_barrier(0);                                               \
        __builtin_amdgcn_s_barrier();                                                    \
        asm volatile("s_waitcnt lgkmcnt(0)" ::: "memory");                               \
        __builtin_amdgcn_sched_barrier(0);                                               \
        __builtin_amdgcn_s_setprio(1);                                                   \
        _Pragma("unroll")                                                                \
        for (int m = 0; m < 4; ++m)                                                      \
            _Pragma("unroll")                                                            \
            for (int n = 0; n < 4; ++n)                                                  \
                acc[m][n] = __builtin_amdgcn_mfma_f32_16x16x32_bf16(af[m], bf[n], acc[m][n], 0, 0, 0); \
        __builtin_amdgcn_s_setprio(0);                                                   \
        __builtin_amdgcn_sched_barrier(0);                                               \
        __builtin_amdgcn_s_barrier();                                                    \
        __builtin_amdgcn_sched_barrier(0);                                               \
        _Pragma("unroll")                                                                \
        for (int m = 0; m < 4; ++m)                                                      \
            af[m] = *reinterpret_cast<const short8*>(&lds[B0 + 8192 + afBase + (m + 4) * 512]); \
        if (kt + 2 < 16) STG(kt + 2, 0, 1);                                              \
        __builtin_amdgcn_sched_barrier(0);                                               \
        __builtin_amdgcn_s_barrier();                                                    \
        asm volatile("s_waitcnt lgkmcnt(0)" ::: "memory");                               \
        __builtin_amdgcn_sched_barrier(0);                                               \
        __builtin_amdgcn_s_setprio(1);                                                   \
        _Pragma("unroll")                                                                \
        for (int m = 0; m < 4; ++m)                                                      \
            _Pragma("unroll")                                                            \
            for (int n = 0; n < 4; ++n)                                                  \
                acc[m + 4][n] = __builtin_amdgcn_mfma_f32_16x16x32_bf16(af[m], bf[n], acc[m + 4][n], 0, 0, 0); \
        __builtin_amdgcn_s_setprio(0);                                                   \
        __builtin_amdgcn_sched_barrier(0);                                               \
        if (kt < 15) { asm volatile("s_waitcnt vmcnt(4)" ::: "memory"); }                \
        else         { asm volatile("s_waitcnt vmcnt(0)" ::: "memory"); }                \
        __builtin_amdgcn_sched_barrier(0);                                               \
        __builtin_amdgcn_s_barrier();                                                    \
        __builtin_amdgcn_sched_barrier(0);                                               \
    }

// ---------------- GEMM1: [16384,3072] = x @ qkv_w^T, LDS-staged epilogue ----------------
// Outputs: q_b[bh][j][d], v_b[bh][j][d] (row-major), kt_g[bh][c][j], vt_g[bh][d][j] (transposed).
__global__ __launch_bounds__(512, 2) void k_gemm1_256(
    const u16* __restrict__ A,   // [16384][1024]
    const u16* __restrict__ Bw,  // [3072][1024]
    const float* __restrict__ bias, const float* __restrict__ pos_enc,
    u16* __restrict__ q, u16* __restrict__ ktg, u16* __restrict__ v, u16* __restrict__ vtg)
{
    __shared__ u16 lds[65536];   // 128 KiB (K-loop dbuf, then 256x256 u16 C-tile)
    const int lid = blockIdx.y * 12 + blockIdx.x;            // nwg = 768, %8==0
    const int swz = (lid & 7) * 96 + (lid >> 3);
    const int bcol = (swz % 12) * 256;
    const int brow = (swz / 12) * 256;

    GEMM256_8PH()

    // ---- epilogue: stage C-tile in LDS (chunk-XOR swizzle cc^=(row&7)), coalesced stores ----
    const int part = bcol >> 10;                 // 0=q 1=k 2=v, uniform per block
    {
        const int row_l = wr * 128 + (l >> 4) * 4;
        const int col_l = wc * 64 + fr;
        #pragma unroll
        for (int n = 0; n < 4; ++n) {
            const int col = col_l + n * 16;
            const int gc = bcol + col;
            const int c = gc & 1023;
            float bv = bias[gc];
            if (part == 1) bv += pos_enc[c];
            const int cc = col >> 3, in = col & 7;
            #pragma unroll
            for (int m = 0; m < 8; ++m)
                #pragma unroll
                for (int j = 0; j < 4; ++j) {
                    const int row = row_l + m * 16 + j;
                    float val = acc[m][n][j] + bv;
                    if (part != 2) val = fmaxf(val, 0.f);
                    lds[row * 256 + ((cc ^ (row & 7)) << 3) + in] = f2b(val);
                }
        }
    }
    __syncthreads();
    const int b_ = brow >> 12, i0 = brow & 4095;
    if (part != 1) {
        // row-major coalesced store: q_b or v_b  [bh][j][d]
        u16* dst = (part == 0) ? q : v;
        #pragma unroll
        for (int it = 0; it < 16; ++it) {
            const int id = it * 512 + t;
            const int row = id >> 5, cc = id & 31;
            short8 val = *reinterpret_cast<const short8*>(&lds[row * 256 + ((cc ^ (row & 7)) << 3)]);
            const int c2 = (bcol + cc * 8) & 1023;
            const int h2 = c2 >> 6, d2 = c2 & 63;
            *reinterpret_cast<short8*>(
                &dst[((size_t)(b_ * NH + h2) * NN + i0 + row) * HDIM + d2]) = val;
        }
    }
    if (part != 0) {
        // transposed coalesced store: kt_g[bh][c][j] or vt_g[bh][d][j]
        u16* dstT = (part == 1) ? ktg : vtg;
        #pragma unroll
        for (int it = 0; it < 16; ++it) {
            const int id = it * 512 + t;
            const int cl = id & 255, jc = id >> 8;   // c-local, j-chunk (8 rows)
            short8 vv;
            #pragma unroll
            for (int rr = 0; rr < 8; ++rr)
                vv[rr] = (short)lds[(jc * 8 + rr) * 256 + (((cl >> 3) ^ rr) << 3) + (cl & 7)];
            const int c2 = (bcol + cl) & 1023;
            const int h2 = c2 >> 6, d2 = c2 & 63;
            *reinterpret_cast<short8*>(
                &dstT[((size_t)(b_ * NH + h2) * HDIM + d2) * NN + i0 + jc * 8]) = vv;
        }
    }
}

// ---------------- GEMM2: [16384,1024] = out2 @ proj_w^T + b (fp32 out) ----------------
__global__ __launch_bounds__(512, 2) void k_gemm2_256(
    const u16* __restrict__ A, const u16* __restrict__ Bw,
    const float* __restrict__ bias, float* __restrict__ out)
{
    __shared__ u16 lds[65536];
    const int lid = blockIdx.y * 4 + blockIdx.x;             // nwg = 256, %8==0
    const int swz = (lid & 7) * 32 + (lid >> 3);
    const int bcol = (swz % 4) * 256;
    const int brow = (swz / 4) * 256;

    GEMM256_8PH()

    const int col_base = bcol + wc * 64 + fr;
    const int row_base = brow + wr * 128 + (l >> 4) * 4;
    #pragma unroll
    for (int n = 0; n < 4; ++n) {
        const int gc = col_base + n * 16;
        const float bv = bias[gc];
        #pragma unroll
        for (int m = 0; m < 8; ++m)
            #pragma unroll
            for (int j = 0; j < 4; ++j) {
                const int gr = row_base + m * 16 + j;
                out[(size_t)gr * CDIM + gc] = acc[m][n][j] + bv;
            }
    }
}

// ---------------- K2: kv via MFMA on transposed layouts (no LDS transpose) --------------
// kvt_partial[d][c] = sum_j vt[d][j] * kt[c][j]^T ; ksum row via all-ones A fragment.
__global__ __launch_bounds__(256) void k_kv_mfma(
    const u16* __restrict__ ktg, const u16* __restrict__ vtg,
    float* __restrict__ part)   // [4 chunks][64 bh][5120]
{
    __shared__ float red[4][5120];   // 80 KB
    const int t = threadIdx.x, l = t & 63, w = t >> 6;
    const int bh = blockIdx.x, ch = blockIdx.y;
    const u16* kb = ktg + (size_t)bh * HDIM * NN;
    const u16* vb = vtg + (size_t)bh * HDIM * NN;
    const int j0 = ch * 1024 + w * 256;
    const int fr = l & 15, kf = (l >> 4) * 8;

    f32x4 acc[5][4];
    #pragma unroll
    for (int m = 0; m < 5; ++m)
        #pragma unroll
        for (int n = 0; n < 4; ++n) acc[m][n] = (f32x4){0.f, 0.f, 0.f, 0.f};
    short8 ones;
    #pragma unroll
    for (int i = 0; i < 8; ++i) ones[i] = (short)0x3F80;   // bf16 1.0

    for (int js = 0; js < 256; js += 32) {
        const int jb = j0 + js + kf;
        short8 a[4], b[4];
        #pragma unroll
        for (int m = 0; m < 4; ++m)
            a[m] = *reinterpret_cast<const short8*>(&vb[(size_t)(m * 16 + fr) * NN + jb]);
        #pragma unroll
        for (int n = 0; n < 4; ++n)
            b[n] = *reinterpret_cast<const short8*>(&kb[(size_t)(n * 16 + fr) * NN + jb]);
        #pragma unroll
        for (int m = 0; m < 4; ++m)
            #pragma unroll
            for (int n = 0; n < 4; ++n)
                acc[m][n] = __builtin_amdgcn_mfma_f32_16x16x32_bf16(a[m], b[n], acc[m][n], 0, 0, 0);
        #pragma unroll
        for (int n = 0; n < 4; ++n)
            acc[4][n] = __builtin_amdgcn_mfma_f32_16x16x32_bf16(ones, b[n], acc[4][n], 0, 0, 0);
    }
    // C/D layout: col = l&15, row = (l>>4)*4 + j  [m89]
    #pragma unroll
    for (int m = 0; m < 5; ++m)
        #pragma unroll
        for (int n = 0; n < 4; ++n)
            #pragma unroll
            for (int j = 0; j < 4; ++j)
                red[w][(m * 16 + (l >> 4) * 4 + j) * 64 + fr + n * 16] = acc[m][n][j];
    __syncthreads();
    float* po = part + ((size_t)ch * BH + bh) * 5120;
    for (int i = t; i < 5120; i += 256)
        po[i] = red[0][i] + red[1][i] + red[2][i] + red[3][i];
}

// ---------------- K3: reduce 4 chunk-partials -> kvt bf16 [80][64] per head ------------
__global__ __launch_bounds__(256) void k_kv_red(
    const float* __restrict__ part, u16* __restrict__ kvt)
{
    const int bh = blockIdx.x, t = threadIdx.x;
    u16* base = kvt + bh * 5120;
    for (int i = t; i < 5120; i += 256) {
        float s = part[(size_t)(0 * BH + bh) * 5120 + i]
                + part[(size_t)(1 * BH + bh) * 5120 + i]
                + part[(size_t)(2 * BH + bh) * 5120 + i]
                + part[(size_t)(3 * BH + bh) * 5120 + i];
        base[i] = f2b(s);
    }
}

// ---------------- K4: MFMA attention finish + depthwise conv (unchanged) ----------------
__global__ __launch_bounds__(256) void k_attn_mfma(
    const u16* __restrict__ q, const u16* __restrict__ v,
    const u16* __restrict__ kvt,
    const float* __restrict__ dwc_w, const float* __restrict__ dwc_b,
    u16* __restrict__ out2)
{
    __shared__ u16 att[4][64 * 68];
    const int t = threadIdx.x;
    const int l = t & 63, w = t >> 6;
    const int bh = blockIdx.x;
    const int tb = blockIdx.y * 256 + w * 64;
    const size_t hb = (size_t)bh * NN * HDIM;
    const u16* qb  = q + hb + (size_t)tb * HDIM;
    const u16* kvb = kvt + bh * 5120;

    const int fr = l & 15;
    const int kfrag = (l >> 4) * 8;

    short8 bfr[5][2];
    #pragma unroll
    for (int n = 0; n < 5; ++n)
        #pragma unroll
        for (int ks = 0; ks < 2; ++ks)
            bfr[n][ks] = *reinterpret_cast<const short8*>(&kvb[(n * 16 + fr) * 64 + ks * 32 + kfrag]);

    f32x4 acc[4][5];
    #pragma unroll
    for (int m = 0; m < 4; ++m)
        #pragma unroll
        for (int n = 0; n < 5; ++n) acc[m][n] = (f32x4){0.f, 0.f, 0.f, 0.f};

    #pragma unroll
    for (int m = 0; m < 4; ++m)
        #pragma unroll
        for (int ks = 0; ks < 2; ++ks) {
            short8 a = *reinterpret_cast<const short8*>(&qb[(m * 16 + fr) * 64 + ks * 32 + kfrag]);
            #pragma unroll
            for (int n = 0; n < 5; ++n)
                acc[m][n] = __builtin_amdgcn_mfma_f32_16x16x32_bf16(a, bfr[n][ks], acc[m][n], 0, 0, 0);
        }

    #pragma unroll
    for (int m = 0; m < 4; ++m)
        #pragma unroll
        for (int j = 0; j < 4; ++j) {
            const float den = __shfl(acc[m][4][j], l & 48);
            const float z = 1.f / (den + 1e-6f);
            const int row = m * 16 + (l >> 4) * 4 + j;
            #pragma unroll
            for (int n = 0; n < 4; ++n)
                att[w][row * 68 + fr + n * 16] = f2b(acc[m][n][j] * z);
        }
    __syncthreads();

    const int d = l;
    float w5[5];
    #pragma unroll
    for (int dh = 0; dh < 5; ++dh) w5[dh] = dwc_w[d * 25 + dh * 5 + 2];
    const float cbias = dwc_b[d];
    const int b_ = bh >> 4, h_ = bh & 15;
    u16* obase = out2 + (size_t)b_ * NN * CDIM + (size_t)h_ * 64 + d;
    float win[5];
    #pragma unroll
    for (int p = 0; p < 4; ++p) {
        const int src = tb - 2 + p;
        win[p] = (src >= 0 && src < NN) ? b2f(v[hb + (size_t)src * 64 + d]) : 0.f;
    }
    for (int it = 0; it < 64; ++it) {
        const int srcn = tb + it + 2;
        win[4] = (srcn < NN) ? b2f(v[hb + (size_t)srcn * 64 + d]) : 0.f;
        const float fm = cbias + w5[0] * win[0] + w5[1] * win[1] + w5[2] * win[2]
                               + w5[3] * win[3] + w5[4] * win[4];
        const float attn = b2f((short)att[w][it * 68 + d]);
        obase[(size_t)(tb + it) * CDIM] = f2b(attn + fm);
        win[0] = win[1]; win[1] = win[2]; win[2] = win[3]; win[3] = win[4];
    }
}

extern "C" void kernel_launch(void* const* d_in, const int* in_sizes, int n_in,
                              void* d_out, int out_size, void* d_ws, size_t ws_size,
                              hipStream_t stream)
{
    const float* x       = (const float*)d_in[0];
    const float* qkv_w   = (const float*)d_in[1];
    const float* qkv_b   = (const float*)d_in[2];
    const float* proj_w  = (const float*)d_in[3];
    const float* proj_b  = (const float*)d_in[4];
    const float* pos_enc = (const float*)d_in[5];
    const float* dwc_w   = (const float*)d_in[6];
    const float* dwc_b   = (const float*)d_in[7];

    const size_t QKV = 16777216;
    char* p = (char*)d_ws;
    u16* q_b    = (u16*)p;               p += QKV * 2;
    u16* ktg    = (u16*)p;               p += QKV * 2;  // reused as out2 after K2
    u16* v_b    = (u16*)p;               p += QKV * 2;
    u16* vtg    = (u16*)p;               p += QKV * 2;
    u16* x_b    = (u16*)p;               p += QKV * 2;
    u16* qkvw_b = (u16*)p;               p += (size_t)3145728 * 2;
    u16* projw_b= (u16*)p;               p += (size_t)1048576 * 2;
    float* part = (float*)p;             p += (size_t)4 * BH * 5120 * 4;
    u16* kvt    = (u16*)p;               p += (size_t)(BH * 5120) * 2;
    const size_t need_bytes = (size_t)(p - (char*)d_ws);

    if (ws_size < need_bytes) {
        const float diag = 4096.0f + (float)(ws_size >> 20);
        k_fill_diag<<<(out_size + 255) / 256, 256, 0, stream>>>((float*)d_out, out_size, diag);
        return;
    }

    u16* out2 = ktg;            // ktg dead after k_kv_mfma
    float* out = (float*)d_out;

    k_f32_to_bf16<<<16384, 256, 0, stream>>>(x,      x_b,     4194304);
    k_f32_to_bf16<<< 3072, 256, 0, stream>>>(qkv_w,  qkvw_b,   786432);
    k_f32_to_bf16<<< 1024, 256, 0, stream>>>(proj_w, projw_b,  262144);

    k_gemm1_256 <<<dim3(12, 64), 512, 0, stream>>>(x_b, qkvw_b, qkv_b, pos_enc, q_b, ktg, v_b, vtg);
    k_kv_mfma   <<<dim3(64, 4),  256, 0, stream>>>(ktg, vtg, part);
    k_kv_red    <<<64,           256, 0, stream>>>(part, kvt);
    k_attn_mfma <<<dim3(64, 16), 256, 0, stream>>>(q_b, v_b, kvt, dwc_w, dwc_b, out2);
    k_gemm2_256 <<<dim3(4, 64),  512, 0, stream>>>(out2, projw_b, proj_b, out);
}